// Round 14
// baseline (964.856 us; speedup 1.0000x reference)
//
#include <hip/hip_runtime.h>
#include <hip/hip_bf16.h>

#define NN      2048
#define NSTEPS  2047
#define MROWS   8192
#define PADK    8

typedef __attribute__((ext_vector_type(8))) __bf16 bf16x8;
typedef __attribute__((ext_vector_type(4))) float  f32x4;
typedef __attribute__((ext_vector_type(2))) float  f32x2;

struct LeafOuts { unsigned short* p[8]; };

__device__ __forceinline__ unsigned short f2bf(float f) {
  unsigned int u = __float_as_uint(f);
  u += 0x7fffu + ((u >> 16) & 1u);   // RNE
  return (unsigned short)(u >> 16);
}

__device__ __forceinline__ void gload_lds16(const void* g, void* l) {
  __builtin_amdgcn_global_load_lds((const __attribute__((address_space(1))) void*)g,
                                   (__attribute__((address_space(3))) void*)l, 16, 0, 0);
}

// DPP wave-wide lane shifts (VALU pipe). Verified rounds 6-13.
template<int CTRL>
__device__ __forceinline__ float dppf(float v) {
  return __int_as_float(__builtin_amdgcn_update_dpp(
      __float_as_int(v), __float_as_int(v), CTRL, 0xf, 0xf, false));
}
#define DPP_UP 0x138
#define DPP_DN 0x130

// Packed fp32 rotation math. Verified rounds 7-13.
__device__ __forceinline__ f32x2 pk_smul(f32x2 cs, f32x2 v) {
  f32x2 d;
  asm("v_pk_mul_f32 %0, %1, %2 op_sel:[1,0] op_sel_hi:[1,1]"
      : "=v"(d) : "v"(cs), "v"(v));
  return d;
}
__device__ __forceinline__ f32x2 pk_cfma(f32x2 cs, f32x2 v, f32x2 a) {
  f32x2 d;
  asm("v_pk_fma_f32 %0, %1, %2, %3 op_sel:[0,0,0] op_sel_hi:[0,1,1]"
      : "=v"(d) : "v"(cs), "v"(v), "v"(a));
  return d;
}
__device__ __forceinline__ f32x2 pk_cfma_neg(f32x2 cs, f32x2 v, f32x2 a) {
  f32x2 d;
  asm("v_pk_fma_f32 %0, %1, %2, %3 op_sel:[0,0,0] op_sel_hi:[0,1,1] neg_lo:[0,0,1] neg_hi:[0,0,1]"
      : "=v"(d) : "v"(cs), "v"(v), "v"(a));
  return d;
}

// ---- angles -> (cos,sin), layout cs[step][pair] (8 KB/slice)
__global__ __launch_bounds__(256) void prep_kernel(
    const float* __restrict__ angles, float2* __restrict__ cs) {
  int idx = blockIdx.x * 256 + threadIdx.x;
  if (idx >= NSTEPS * 1024) return;
  float s, c;
  sincosf(angles[idx], &s, &c);
  cs[idx] = make_float2(c, s);
}

// ---- x fp32 -> bf16
__global__ __launch_bounds__(256) void cvt_kernel(
    const float4* __restrict__ x, ushort4* __restrict__ xb, int n4) {
  int idx = blockIdx.x * 256 + threadIdx.x;
  if (idx >= n4) return;
  float4 v = x[idx];
  ushort4 o;
  o.x = f2bf(v.x); o.y = f2bf(v.y); o.z = f2bf(v.z); o.w = f2bf(v.w);
  xb[idx] = o;
}

// ---- zero scratch region (grid-stride)
__global__ __launch_bounds__(256) void zero_kernel(uint4* __restrict__ p, int n) {
  int idx = blockIdx.x * 256 + threadIdx.x;
  const int stride = gridDim.x * 256;
  const uint4 z = make_uint4(0, 0, 0, 0);
  for (; idx < n; idx += stride) p[idx] = z;
}

// ---- leaf: build chunk matrix B_c rows by windowed wave-autonomous conveyor.
// Body byte-identical to round-12/13-verified kernel. XCD-aligned chunk mapping:
// cl = bid & cmask (chunk in LOW bits -> all blocks of a chunk land on one XCD
// under round-robin bid%8 placement; each XCD's L2 then holds only its chunk's
// 2 MB cs region instead of all 16.8 MB).
template<int LC>
__global__ __launch_bounds__(256) void leaf_kernel(
    const char* __restrict__ csb, LeafOuts outs, int c_base, int first_rm,
    int cmask, int cshift) {
  const int tid  = threadIdx.x;
  const int lane = tid & 63;
  const int cl   = blockIdx.x & cmask;                   // chunk-local (XCD-aligned)
  const int v    = ((blockIdx.x >> cshift) << 2) + (tid >> 6);
  const int c    = c_base + cl;
  const int t0   = 254 * c;
  unsigned short* out = outs.p[cl];
  const bool rm = (first_rm != 0) && (cl == 0);

  const int pA = 2 * v, pB = 2 * v + 1;
  const int kA = (pA <= 1023) ? pA : 2047 - pA;
  const int kBp = (pB <= 1023) ? pB : 2047 - pB;
  const int kmin = min(kA, kBp);
  int kb = (kmin - 254) & ~1;
  kb = min(max(kb, 0), 512);
  const bool l0 = (lane == 0), l63 = (lane == 63);
  const bool c0l0  = (kb == 0)   && l0;
  const bool cTl63 = (kb == 512) && l63;

  // state: elem e <-> pair k = kb + 8*lane + e; F slot = pos k, S slot = pos 2047-k
  f32x2 FF[8], SS[8];
#pragma unroll
  for (int e = 0; e < 8; ++e) {
    const int k = kb + 8 * lane + e, m = 2047 - k;
    FF[e] = (f32x2){(k == pA) ? 1.f : 0.f, (k == pB) ? 1.f : 0.f};
    SS[e] = (f32x2){(m == pA) ? 1.f : 0.f, (m == pB) ? 1.f : 0.f};
  }

  // cs: lane's 8 pairs = 64B at slice + kb*8 + 64*lane (kb even -> 16B aligned)
  const char* gpE = csb + (size_t)t0 * 8192 + kb * 8 + 64 * lane;
  const char* gpO = gpE + 8192;
  float4 cE0 = ((const float4*)gpE)[0], cE1 = ((const float4*)gpE)[1];
  float4 cE2 = ((const float4*)gpE)[2], cE3 = ((const float4*)gpE)[3];
  float4 cO0 = ((const float4*)gpO)[0], cO1 = ((const float4*)gpO)[1];
  float4 cO2 = ((const float4*)gpO)[2], cO3 = ((const float4*)gpO)[3];
  gpE += 16384; gpO += 16384;

#define CP(CV, K) (((const f32x2*)&(CV))[(K)])

#define ROTE(E, CPp) { \
    const int rF = ((E) - PHI) & 7, rS = ((E) + PHI) & 7; \
    const f32x2 cp_ = (CPp); \
    const f32x2 t_ = pk_smul(cp_, SS[rS]); \
    const f32x2 u_ = pk_smul(cp_, FF[rF]); \
    FF[rF] = pk_cfma(cp_, FF[rF], t_); \
    SS[rS] = pk_cfma_neg(cp_, SS[rS], u_); }

#define LSTEP(PHI_, C0, C1, C2, C3, GP) { \
    const int PHI = (PHI_); \
    const int pF = (7 - PHI) & 7, pT = (8 - PHI) & 7; \
    ROTE(0, CP(C0, 0)) ROTE(1, CP(C0, 1)) \
    ROTE(2, CP(C1, 0)) ROTE(3, CP(C1, 1)) \
    ROTE(4, CP(C2, 0)) ROTE(5, CP(C2, 1)) \
    ROTE(6, CP(C3, 0)) ROTE(7, CP(C3, 1)) \
    const f32x2 Fo = FF[pF], So = SS[PHI], St = FF[pT]; \
    f32x2 fi, sd; \
    fi.x = dppf<DPP_UP>(Fo.x); fi.y = dppf<DPP_UP>(Fo.y); \
    sd.x = dppf<DPP_DN>(So.x); sd.y = dppf<DPP_DN>(So.y); \
    C0 = ((const float4*)GP)[0]; C1 = ((const float4*)GP)[1]; \
    C2 = ((const float4*)GP)[2]; C3 = ((const float4*)GP)[3]; \
    GP += 16384; \
    const f32x2 z2 = {0.f, 0.f}; \
    const f32x2 xF = c0l0 ? St : z2; \
    const f32x2 xS = cTl63 ? Fo : z2; \
    FF[pF]  = l0  ? xF : fi; \
    SS[PHI] = l63 ? xS : sd; \
    FF[pT]  = c0l0 ? So : FF[pT]; \
  }

  constexpr int ITERS = LC / 8;
  constexpr int TAIL  = LC & 7;
#pragma unroll 1
  for (int it = 0; it < ITERS; ++it) {
    LSTEP(0, cE0, cE1, cE2, cE3, gpE)
    LSTEP(1, cO0, cO1, cO2, cO3, gpO)
    LSTEP(2, cE0, cE1, cE2, cE3, gpE)
    LSTEP(3, cO0, cO1, cO2, cO3, gpO)
    LSTEP(4, cE0, cE1, cE2, cE3, gpE)
    LSTEP(5, cO0, cO1, cO2, cO3, gpO)
    LSTEP(6, cE0, cE1, cE2, cE3, gpE)
    LSTEP(7, cO0, cO1, cO2, cO3, gpO)
  }
  if constexpr (TAIL >= 1) LSTEP(0, cE0, cE1, cE2, cE3, gpE)
  if constexpr (TAIL >= 2) LSTEP(1, cO0, cO1, cO2, cO3, gpO)
  if constexpr (TAIL >= 3) LSTEP(2, cE0, cE1, cE2, cE3, gpE)
  if constexpr (TAIL >= 4) LSTEP(3, cO0, cO1, cO2, cO3, gpO)
  if constexpr (TAIL >= 5) LSTEP(4, cE0, cE1, cE2, cE3, gpE)
  if constexpr (TAIL >= 6) LSTEP(5, cO0, cO1, cO2, cO3, gpO)
  if constexpr (TAIL >= 7) LSTEP(6, cE0, cE1, cE2, cE3, gpE)

  // readout at T=LC: F elem e in FF[(e-LC)&7]; S elem e in SS[(e+LC)&7].
  constexpr int RPH = LC & 7;
  const int tend = t0 + LC;
  const int rA = (pA == 0) ? 0 : ((pA - 1 - t0 + 4094) % 2047) + 1;
  const int rB = ((pB - 1 - t0 + 4094) % 2047) + 1;
#pragma unroll
  for (int e = 0; e < 8; ++e) {
    const int k = kb + 8 * lane + e;
    const int lF = (k == 0) ? 0 : ((k - 1 - tend + 4094) % 2047) + 1;
    const int lS = ((2046 - k - tend + 4094) % 2047) + 1;
    const f32x2 fv = FF[(e - RPH) & 7];
    const f32x2 sv = SS[(e + RPH) & 7];
    if (rm) {
      out[(size_t)rA * NN + lF] = f2bf(fv.x);
      out[(size_t)rB * NN + lF] = f2bf(fv.y);
      out[(size_t)rA * NN + lS] = f2bf(sv.x);
      out[(size_t)rB * NN + lS] = f2bf(sv.y);
    } else {
      out[(size_t)lF * NN + rA] = f2bf(fv.x);
      out[(size_t)lF * NN + rB] = f2bf(fv.y);
      out[(size_t)lS * NN + rA] = f2bf(sv.x);
      out[(size_t)lS * NN + rB] = f2bf(sv.y);
    }
  }
}

// κ-range of a cyclic position arc [a, a+len-1] in [1..2047], κ(p)=min(p,2047-p)
__device__ __forceinline__ void arc_kr(int a, int len, int& lo, int& hi) {
  int last = a + len - 1; if (last > 2047) last -= 2047;
  const int k1 = min(a, 2047 - a), k2 = min(last, 2047 - last);
  lo = min(k1, k2); hi = max(k1, k2);
  int d;
  d = 1023 - a; if (d < 0) d += 2047; if (d < len) hi = 1023;
  d = 1024 - a; if (d < 0) d += 2047; if (d < len) hi = 1023;
  d = 2047 - a; if (d < 0) d += 2047; if (d < len) lo = 0;
  d = 1    - a; if (d < 0) d += 2047; if (d < len) lo = min(lo, 1);
}

#define BM 128
#define BN 128
#define BK 32

// ---- comp: C = A * Bt^T (2048^3), bf16 out, K-tiles band-skipped by cone test.
__global__ __launch_bounds__(256) void comp_kernel(
    const unsigned short* __restrict__ A, const unsigned short* __restrict__ B,
    unsigned short* __restrict__ C, int ta, int tb) {
  __shared__ unsigned short As[BM * BK];
  __shared__ unsigned short Bs[BN * BK];
  const int tid  = threadIdx.x;
  const int lane = tid & 63;
  const int wave = tid >> 6;
  const int bm = blockIdx.x, bn = blockIdx.y;
  const int wm = wave & 1, wn = wave >> 1;

  const int n0 = bn * BN;
  int qlo, qhi;
  {
    const int nfirst = (n0 == 0) ? 1 : n0;
    const int a = ((nfirst - 1 + tb) % 2047) + 1;
    const int len = (n0 == 0) ? (BN - 1) : BN;
    arc_kr(a, len, qlo, qhi);
    if (n0 == 0) qlo = 0;
  }
  const int L = tb - ta;
  const int KAc = max(qlo - L - PADK, 0);
  const int KBc = min(qhi + L + PADK, 1023);

  const int srow = wave * 16 + (lane >> 2);
  const int scol = (lane & 3) * 8;
  const unsigned short* Ag = A + (size_t)(bm * BM + srow) * NN + scol;
  const unsigned short* Bg = B + (size_t)(bn * BN + srow) * NN + scol;

  const int fm = lane & 15;
  const int kbr = lane >> 4;

  f32x4 acc[4][4];
#pragma unroll
  for (int a_ = 0; a_ < 4; ++a_)
#pragma unroll
    for (int b_ = 0; b_ < 4; ++b_) acc[a_][b_] = (f32x4){0.f, 0.f, 0.f, 0.f};

  for (int kt = 0; kt < NN / BK; ++kt) {
    const int k0 = kt * BK;
    {
      const int kfirst = (k0 == 0) ? 1 : k0;
      const int a2 = ((kfirst - 1 + ta) % 2047) + 1;
      const int len2 = (k0 == 0) ? (BK - 1) : BK;
      int tlo, thi; arc_kr(a2, len2, tlo, thi);
      if (k0 == 0) tlo = 0;
      if (thi < KAc || tlo > KBc) continue;
    }
#pragma unroll
    for (int it = 0; it < 2; ++it) {
      gload_lds16(Ag + (size_t)(it * 64) * NN + k0, &As[wave * 512 + it * 2048]);
      gload_lds16(Bg + (size_t)(it * 64) * NN + k0, &Bs[wave * 512 + it * 2048]);
    }
    __syncthreads();

    bf16x8 af[4], bfr[4];
#pragma unroll
    for (int a_ = 0; a_ < 4; ++a_)
      af[a_] = *(const bf16x8*)&As[(wm * 64 + a_ * 16 + fm) * BK + kbr * 8];
#pragma unroll
    for (int b_ = 0; b_ < 4; ++b_)
      bfr[b_] = *(const bf16x8*)&Bs[(wn * 64 + b_ * 16 + fm) * BK + kbr * 8];
#pragma unroll
    for (int a_ = 0; a_ < 4; ++a_)
#pragma unroll
      for (int b_ = 0; b_ < 4; ++b_)
        acc[a_][b_] = __builtin_amdgcn_mfma_f32_16x16x32_bf16(af[a_], bfr[b_], acc[a_][b_], 0, 0, 0);
    __syncthreads();
  }

  const int row_in = (lane >> 4) * 4;
#pragma unroll
  for (int a_ = 0; a_ < 4; ++a_) {
#pragma unroll
    for (int b_ = 0; b_ < 4; ++b_) {
      const int gn = bn * BN + wn * 64 + b_ * 16 + fm;
#pragma unroll
      for (int v = 0; v < 4; ++v) {
        const int gm = bm * BM + wm * 64 + a_ * 16 + row_in + v;
        C[(size_t)gm * NN + gn] = f2bf(acc[a_][b_][v]);
      }
    }
  }
}

// ---- final: out = x_bf16 * U^T + bias (fp32 out). Verified rounds 1-13.
__global__ __launch_bounds__(256) void gemm_kernel(
    const unsigned short* __restrict__ A, const unsigned short* __restrict__ B,
    const float* __restrict__ bias, float* __restrict__ C) {
  __shared__ unsigned short As[BM * BK];
  __shared__ unsigned short Bs[BN * BK];
  const int tid  = threadIdx.x;
  const int lane = tid & 63;
  const int wave = tid >> 6;
  const int bm = blockIdx.x, bn = blockIdx.y;
  const int wm = wave & 1, wn = wave >> 1;

  const int srow = wave * 16 + (lane >> 2);
  const int scol = (lane & 3) * 8;
  const unsigned short* Ag = A + (size_t)(bm * BM + srow) * NN + scol;
  const unsigned short* Bg = B + (size_t)(bn * BN + srow) * NN + scol;

  const int fm = lane & 15;
  const int kbr = lane >> 4;

  f32x4 acc[4][4];
#pragma unroll
  for (int a_ = 0; a_ < 4; ++a_)
#pragma unroll
    for (int b_ = 0; b_ < 4; ++b_) acc[a_][b_] = (f32x4){0.f, 0.f, 0.f, 0.f};

  for (int kt = 0; kt < NN / BK; ++kt) {
    const int k0 = kt * BK;
#pragma unroll
    for (int it = 0; it < 2; ++it) {
      gload_lds16(Ag + (size_t)(it * 64) * NN + k0, &As[wave * 512 + it * 2048]);
      gload_lds16(Bg + (size_t)(it * 64) * NN + k0, &Bs[wave * 512 + it * 2048]);
    }
    __syncthreads();

    bf16x8 af[4], bfr[4];
#pragma unroll
    for (int a_ = 0; a_ < 4; ++a_)
      af[a_] = *(const bf16x8*)&As[(wm * 64 + a_ * 16 + fm) * BK + kbr * 8];
#pragma unroll
    for (int b_ = 0; b_ < 4; ++b_)
      bfr[b_] = *(const bf16x8*)&Bs[(wn * 64 + b_ * 16 + fm) * BK + kbr * 8];
#pragma unroll
    for (int a_ = 0; a_ < 4; ++a_)
#pragma unroll
      for (int b_ = 0; b_ < 4; ++b_)
        acc[a_][b_] = __builtin_amdgcn_mfma_f32_16x16x32_bf16(af[a_], bfr[b_], acc[a_][b_], 0, 0, 0);
    __syncthreads();
  }

  const int row_in = (lane >> 4) * 4;
#pragma unroll
  for (int a_ = 0; a_ < 4; ++a_) {
#pragma unroll
    for (int b_ = 0; b_ < 4; ++b_) {
      const int gn = bn * BN + wn * 64 + b_ * 16 + fm;
      const float bv = bias[gn];
#pragma unroll
      for (int v = 0; v < 4; ++v) {
        const int gm = bm * BM + wm * 64 + a_ * 16 + row_in + v;
        C[(size_t)gm * NN + gn] = acc[a_][b_][v] + bv;
      }
    }
  }
}

extern "C" void kernel_launch(void* const* d_in, const int* in_sizes, int n_in,
                              void* d_out, int out_size, void* d_ws, size_t ws_size,
                              hipStream_t stream) {
  const float* x      = (const float*)d_in[0];
  const float* angles = (const float*)d_in[1];
  const float* bias   = (const float*)d_in[2];
  float* out = (float*)d_out;

  char* ws = (char*)d_ws;
  unsigned short* P0  = (unsigned short*)(ws + 0);         //  8,388,608
  unsigned short* P1  = (unsigned short*)(ws + 8388608);   //  8,388,608
  char*           cs  = ws + 16777216;                     // 16,809,984 (2052 slices)
  unsigned short* B7  = (unsigned short*)(ws + 33587200);  //  8,388,608
  unsigned short* B8  = (unsigned short*)(ws + 41975808);  //  8,388,608 -> end 50,364,416
  unsigned short* xb  = (unsigned short*)(ws + 16777216);  // overlay (after comps)

  // B1..B6 live in d_out (67.1 MB; final gemm overwrites all of d_out at the end)
  char* ob = (char*)d_out;
  unsigned short* B1 = (unsigned short*)(ob + 0);
  unsigned short* B2 = (unsigned short*)(ob + 8388608);
  unsigned short* B3 = (unsigned short*)(ob + 16777216);
  unsigned short* B4 = (unsigned short*)(ob + 25165824);
  unsigned short* B5 = (unsigned short*)(ob + 33554432);
  unsigned short* B6 = (unsigned short*)(ob + 41943040);   // end 50,331,648 <= 67,108,864

  prep_kernel<<<dim3(8188), dim3(256), 0, stream>>>(angles, (float2*)cs);
  zero_kernel<<<dim3(2048), dim3(256), 0, stream>>>((uint4*)ob, 50331648 / 16);
  zero_kernel<<<dim3(1024), dim3(256), 0, stream>>>((uint4*)P0, 8388608 / 16);
  zero_kernel<<<dim3(1024), dim3(256), 0, stream>>>((uint4*)(ws + 33587200), 16777216 / 16);

  // single merged leaf dispatch, XCD-aligned: chunk = bid & 7 (one chunk per XCD)
  LeafOuts lo_main;
  lo_main.p[0] = P0; lo_main.p[1] = B1; lo_main.p[2] = B2; lo_main.p[3] = B3;
  lo_main.p[4] = B4; lo_main.p[5] = B5; lo_main.p[6] = B6; lo_main.p[7] = B7;
  leaf_kernel<254><<<dim3(2048), dim3(256), 0, stream>>>(cs, lo_main, 0, 1, 7, 3);
  // chunk 8 (15 steps)
  LeafOuts lo_tail;
  for (int i = 0; i < 8; ++i) lo_tail.p[i] = B8;
  leaf_kernel<15><<<dim3(256), dim3(256), 0, stream>>>(cs, lo_tail, 8, 0, 0, 0);

  // composition chain: P = B0 * B1 * ... * B8
  comp_kernel<<<dim3(16, 16), dim3(256), 0, stream>>>(P0, B1, P1,  254,  508);
  comp_kernel<<<dim3(16, 16), dim3(256), 0, stream>>>(P1, B2, P0,  508,  762);
  comp_kernel<<<dim3(16, 16), dim3(256), 0, stream>>>(P0, B3, P1,  762, 1016);
  comp_kernel<<<dim3(16, 16), dim3(256), 0, stream>>>(P1, B4, P0, 1016, 1270);
  comp_kernel<<<dim3(16, 16), dim3(256), 0, stream>>>(P0, B5, P1, 1270, 1524);
  comp_kernel<<<dim3(16, 16), dim3(256), 0, stream>>>(P1, B6, P0, 1524, 1778);
  comp_kernel<<<dim3(16, 16), dim3(256), 0, stream>>>(P0, B7, P1, 1778, 2032);
  comp_kernel<<<dim3(16, 16), dim3(256), 0, stream>>>(P1, B8, P0, 2032, 2047);

  // x -> bf16 into overlay (cs/B7/B8 dead now), then final GEMM overwrites d_out
  cvt_kernel<<<dim3(16384), dim3(256), 0, stream>>>((const float4*)x, (ushort4*)xb,
                                                    MROWS * NN / 4);
  gemm_kernel<<<dim3(MROWS / BM, NN / BN), dim3(256), 0, stream>>>(xb, P0, bias, out);
}

// Round 15
// 842.472 us; speedup vs baseline: 1.1453x; 1.1453x over previous
//
#include <hip/hip_runtime.h>
#include <hip/hip_bf16.h>

#define NN      2048
#define NSTEPS  2047
#define MROWS   8192
#define PADK    8

typedef __attribute__((ext_vector_type(8))) __bf16 bf16x8;
typedef __attribute__((ext_vector_type(4))) float  f32x4;
typedef __attribute__((ext_vector_type(2))) float  f32x2;

struct LeafOuts { unsigned short* p[8]; };

__device__ __forceinline__ unsigned short f2bf(float f) {
  unsigned int u = __float_as_uint(f);
  u += 0x7fffu + ((u >> 16) & 1u);   // RNE
  return (unsigned short)(u >> 16);
}

__device__ __forceinline__ void gload_lds16(const void* g, void* l) {
  __builtin_amdgcn_global_load_lds((const __attribute__((address_space(1))) void*)g,
                                   (__attribute__((address_space(3))) void*)l, 16, 0, 0);
}

// DPP wave-wide lane shifts (VALU pipe). Verified rounds 6-14.
template<int CTRL>
__device__ __forceinline__ float dppf(float v) {
  return __int_as_float(__builtin_amdgcn_update_dpp(
      __float_as_int(v), __float_as_int(v), CTRL, 0xf, 0xf, false));
}
#define DPP_UP 0x138
#define DPP_DN 0x130

// Packed fp32 rotation math. Verified rounds 7-14.
__device__ __forceinline__ f32x2 pk_smul(f32x2 cs, f32x2 v) {
  f32x2 d;
  asm("v_pk_mul_f32 %0, %1, %2 op_sel:[1,0] op_sel_hi:[1,1]"
      : "=v"(d) : "v"(cs), "v"(v));
  return d;
}
__device__ __forceinline__ f32x2 pk_cfma(f32x2 cs, f32x2 v, f32x2 a) {
  f32x2 d;
  asm("v_pk_fma_f32 %0, %1, %2, %3 op_sel:[0,0,0] op_sel_hi:[0,1,1]"
      : "=v"(d) : "v"(cs), "v"(v), "v"(a));
  return d;
}
__device__ __forceinline__ f32x2 pk_cfma_neg(f32x2 cs, f32x2 v, f32x2 a) {
  f32x2 d;
  asm("v_pk_fma_f32 %0, %1, %2, %3 op_sel:[0,0,0] op_sel_hi:[0,1,1] neg_lo:[0,0,1] neg_hi:[0,0,1]"
      : "=v"(d) : "v"(cs), "v"(v), "v"(a));
  return d;
}

// ---- angles -> (cos,sin), PLANE layout per 8KB slice:
// [plane(4)][entry(128)][b(2)] float2; pair p = 8*entry + 2*plane + b.
// Lane-contiguous leaf loads (16B stride) <- this round's change.
// Thread t writes linear f2 offset t (coalesced); reads angles via the inverse perm.
__global__ __launch_bounds__(256) void prep_kernel(
    const float* __restrict__ angles, float2* __restrict__ cs) {
  int t = blockIdx.x * 256 + threadIdx.x;
  if (t >= NSTEPS * 1024) return;
  const int slice = t >> 10;
  const int w     = t & 1023;          // f2 index within slice
  const int plane = w >> 8;            // 256 f2 per plane
  const int r     = w & 255;
  const int entry = r >> 1;
  const int b     = r & 1;
  const int p     = 8 * entry + 2 * plane + b;
  float s, c;
  sincosf(angles[slice * 1024 + p], &s, &c);
  cs[t] = make_float2(c, s);
}

// ---- x fp32 -> bf16
__global__ __launch_bounds__(256) void cvt_kernel(
    const float4* __restrict__ x, ushort4* __restrict__ xb, int n4) {
  int idx = blockIdx.x * 256 + threadIdx.x;
  if (idx >= n4) return;
  float4 v = x[idx];
  ushort4 o;
  o.x = f2bf(v.x); o.y = f2bf(v.y); o.z = f2bf(v.z); o.w = f2bf(v.w);
  xb[idx] = o;
}

// ---- zero scratch region (grid-stride)
__global__ __launch_bounds__(256) void zero_kernel(uint4* __restrict__ p, int n) {
  int idx = blockIdx.x * 256 + threadIdx.x;
  const int stride = gridDim.x * 256;
  const uint4 z = make_uint4(0, 0, 0, 0);
  for (; idx < n; idx += stride) p[idx] = z;
}

// ---- leaf: build chunk matrix B_c rows by windowed wave-autonomous conveyor.
// Body identical to r12-14 (verified); cs loads now hit the PLANE layout with
// 16-B lane stride (16 lines/load instead of 64 -> off the L1 line-lookup wall).
// XCD-aligned chunk mapping (cl = bid & cmask) kept from r14.
template<int LC>
__global__ __launch_bounds__(256) void leaf_kernel(
    const char* __restrict__ csb, LeafOuts outs, int c_base, int first_rm,
    int cmask, int cshift) {
  const int tid  = threadIdx.x;
  const int lane = tid & 63;
  const int cl   = blockIdx.x & cmask;
  const int v    = ((blockIdx.x >> cshift) << 2) + (tid >> 6);
  const int c    = c_base + cl;
  const int t0   = 254 * c;
  unsigned short* out = outs.p[cl];
  const bool rm = (first_rm != 0) && (cl == 0);

  const int pA = 2 * v, pB = 2 * v + 1;
  const int kA = (pA <= 1023) ? pA : 2047 - pA;
  const int kBp = (pB <= 1023) ? pB : 2047 - pB;
  const int kmin = min(kA, kBp);
  int kb = (kmin - 254) & ~1;
  kb = min(max(kb, 0), 512);
  const bool l0 = (lane == 0), l63 = (lane == 63);
  const bool c0l0  = (kb == 0)   && l0;
  const bool cTl63 = (kb == 512) && l63;

  // state: elem e <-> pair k = kb + 8*lane + e; F slot = pos k, S slot = pos 2047-k
  f32x2 FF[8], SS[8];
#pragma unroll
  for (int e = 0; e < 8; ++e) {
    const int k = kb + 8 * lane + e, m = 2047 - k;
    FF[e] = (f32x2){(k == pA) ? 1.f : 0.f, (k == pB) ? 1.f : 0.f};
    SS[e] = (f32x2){(m == pA) ? 1.f : 0.f, (m == pB) ? 1.f : 0.f};
  }

  // cs plane addressing: pair kb+8l+2*ep+b lives at plane (m+ep)&3,
  // entry kb8 + ((m+ep)>>2) + l, half b  (m = (kb>>1)&3, kb8 = kb>>3).
  // Lane stride = 16 B -> coalesced.
  const int kb8 = kb >> 3, mm = (kb >> 1) & 3;
  const char* base = csb + (size_t)t0 * 8192 + 16 * lane;
  const char* gE[4];
  const char* gO[4];
#pragma unroll
  for (int ep = 0; ep < 4; ++ep) {
    const int u = mm + ep;
    const int off = (u & 3) * 2048 + (kb8 + (u >> 2)) * 16;
    gE[ep] = base + off;
    gO[ep] = base + off + 8192;
  }
  float4 cE0 = *(const float4*)gE[0], cE1 = *(const float4*)gE[1];
  float4 cE2 = *(const float4*)gE[2], cE3 = *(const float4*)gE[3];   // slice 0
  float4 cO0 = *(const float4*)gO[0], cO1 = *(const float4*)gO[1];
  float4 cO2 = *(const float4*)gO[2], cO3 = *(const float4*)gO[3];   // slice 1
#pragma unroll
  for (int ep = 0; ep < 4; ++ep) { gE[ep] += 16384; gO[ep] += 16384; }  // slices 2,3

#define CP(CV, K) (((const f32x2*)&(CV))[(K)])

#define ROTE(E, CPp) { \
    const int rF = ((E) - PHI) & 7, rS = ((E) + PHI) & 7; \
    const f32x2 cp_ = (CPp); \
    const f32x2 t_ = pk_smul(cp_, SS[rS]); \
    const f32x2 u_ = pk_smul(cp_, FF[rF]); \
    FF[rF] = pk_cfma(cp_, FF[rF], t_); \
    SS[rS] = pk_cfma_neg(cp_, SS[rS], u_); }

#define LSTEP(PHI_, C0, C1, C2, C3, GP) { \
    const int PHI = (PHI_); \
    const int pF = (7 - PHI) & 7, pT = (8 - PHI) & 7; \
    ROTE(0, CP(C0, 0)) ROTE(1, CP(C0, 1)) \
    ROTE(2, CP(C1, 0)) ROTE(3, CP(C1, 1)) \
    ROTE(4, CP(C2, 0)) ROTE(5, CP(C2, 1)) \
    ROTE(6, CP(C3, 0)) ROTE(7, CP(C3, 1)) \
    const f32x2 Fo = FF[pF], So = SS[PHI], St = FF[pT]; \
    f32x2 fi, sd; \
    fi.x = dppf<DPP_UP>(Fo.x); fi.y = dppf<DPP_UP>(Fo.y); \
    sd.x = dppf<DPP_DN>(So.x); sd.y = dppf<DPP_DN>(So.y); \
    C0 = *(const float4*)GP[0]; C1 = *(const float4*)GP[1]; \
    C2 = *(const float4*)GP[2]; C3 = *(const float4*)GP[3]; \
    GP[0] += 16384; GP[1] += 16384; GP[2] += 16384; GP[3] += 16384; \
    const f32x2 z2 = {0.f, 0.f}; \
    const f32x2 xF = c0l0 ? St : z2; \
    const f32x2 xS = cTl63 ? Fo : z2; \
    FF[pF]  = l0  ? xF : fi; \
    SS[PHI] = l63 ? xS : sd; \
    FF[pT]  = c0l0 ? So : FF[pT]; \
  }

  constexpr int ITERS = LC / 8;
  constexpr int TAIL  = LC & 7;
#pragma unroll 1
  for (int it = 0; it < ITERS; ++it) {
    LSTEP(0, cE0, cE1, cE2, cE3, gE)
    LSTEP(1, cO0, cO1, cO2, cO3, gO)
    LSTEP(2, cE0, cE1, cE2, cE3, gE)
    LSTEP(3, cO0, cO1, cO2, cO3, gO)
    LSTEP(4, cE0, cE1, cE2, cE3, gE)
    LSTEP(5, cO0, cO1, cO2, cO3, gO)
    LSTEP(6, cE0, cE1, cE2, cE3, gE)
    LSTEP(7, cO0, cO1, cO2, cO3, gO)
  }
  if constexpr (TAIL >= 1) LSTEP(0, cE0, cE1, cE2, cE3, gE)
  if constexpr (TAIL >= 2) LSTEP(1, cO0, cO1, cO2, cO3, gO)
  if constexpr (TAIL >= 3) LSTEP(2, cE0, cE1, cE2, cE3, gE)
  if constexpr (TAIL >= 4) LSTEP(3, cO0, cO1, cO2, cO3, gO)
  if constexpr (TAIL >= 5) LSTEP(4, cE0, cE1, cE2, cE3, gE)
  if constexpr (TAIL >= 6) LSTEP(5, cO0, cO1, cO2, cO3, gO)
  if constexpr (TAIL >= 7) LSTEP(6, cE0, cE1, cE2, cE3, gE)

  // readout at T=LC: F elem e in FF[(e-LC)&7]; S elem e in SS[(e+LC)&7].
  constexpr int RPH = LC & 7;
  const int tend = t0 + LC;
  const int rA = (pA == 0) ? 0 : ((pA - 1 - t0 + 4094) % 2047) + 1;
  const int rB = ((pB - 1 - t0 + 4094) % 2047) + 1;
#pragma unroll
  for (int e = 0; e < 8; ++e) {
    const int k = kb + 8 * lane + e;
    const int lF = (k == 0) ? 0 : ((k - 1 - tend + 4094) % 2047) + 1;
    const int lS = ((2046 - k - tend + 4094) % 2047) + 1;
    const f32x2 fv = FF[(e - RPH) & 7];
    const f32x2 sv = SS[(e + RPH) & 7];
    if (rm) {
      out[(size_t)rA * NN + lF] = f2bf(fv.x);
      out[(size_t)rB * NN + lF] = f2bf(fv.y);
      out[(size_t)rA * NN + lS] = f2bf(sv.x);
      out[(size_t)rB * NN + lS] = f2bf(sv.y);
    } else {
      out[(size_t)lF * NN + rA] = f2bf(fv.x);
      out[(size_t)lF * NN + rB] = f2bf(fv.y);
      out[(size_t)lS * NN + rA] = f2bf(sv.x);
      out[(size_t)lS * NN + rB] = f2bf(sv.y);
    }
  }
}

// κ-range of a cyclic position arc [a, a+len-1] in [1..2047], κ(p)=min(p,2047-p)
__device__ __forceinline__ void arc_kr(int a, int len, int& lo, int& hi) {
  int last = a + len - 1; if (last > 2047) last -= 2047;
  const int k1 = min(a, 2047 - a), k2 = min(last, 2047 - last);
  lo = min(k1, k2); hi = max(k1, k2);
  int d;
  d = 1023 - a; if (d < 0) d += 2047; if (d < len) hi = 1023;
  d = 1024 - a; if (d < 0) d += 2047; if (d < len) hi = 1023;
  d = 2047 - a; if (d < 0) d += 2047; if (d < len) lo = 0;
  d = 1    - a; if (d < 0) d += 2047; if (d < len) lo = min(lo, 1);
}

#define BM 128
#define BN 128
#define BK 32

// ---- comp: C = A * Bt^T (2048^3), bf16 out, K-tiles band-skipped by cone test.
__global__ __launch_bounds__(256) void comp_kernel(
    const unsigned short* __restrict__ A, const unsigned short* __restrict__ B,
    unsigned short* __restrict__ C, int ta, int tb) {
  __shared__ unsigned short As[BM * BK];
  __shared__ unsigned short Bs[BN * BK];
  const int tid  = threadIdx.x;
  const int lane = tid & 63;
  const int wave = tid >> 6;
  const int bm = blockIdx.x, bn = blockIdx.y;
  const int wm = wave & 1, wn = wave >> 1;

  const int n0 = bn * BN;
  int qlo, qhi;
  {
    const int nfirst = (n0 == 0) ? 1 : n0;
    const int a = ((nfirst - 1 + tb) % 2047) + 1;
    const int len = (n0 == 0) ? (BN - 1) : BN;
    arc_kr(a, len, qlo, qhi);
    if (n0 == 0) qlo = 0;
  }
  const int L = tb - ta;
  const int KAc = max(qlo - L - PADK, 0);
  const int KBc = min(qhi + L + PADK, 1023);

  const int srow = wave * 16 + (lane >> 2);
  const int scol = (lane & 3) * 8;
  const unsigned short* Ag = A + (size_t)(bm * BM + srow) * NN + scol;
  const unsigned short* Bg = B + (size_t)(bn * BN + srow) * NN + scol;

  const int fm = lane & 15;
  const int kbr = lane >> 4;

  f32x4 acc[4][4];
#pragma unroll
  for (int a_ = 0; a_ < 4; ++a_)
#pragma unroll
    for (int b_ = 0; b_ < 4; ++b_) acc[a_][b_] = (f32x4){0.f, 0.f, 0.f, 0.f};

  for (int kt = 0; kt < NN / BK; ++kt) {
    const int k0 = kt * BK;
    {
      const int kfirst = (k0 == 0) ? 1 : k0;
      const int a2 = ((kfirst - 1 + ta) % 2047) + 1;
      const int len2 = (k0 == 0) ? (BK - 1) : BK;
      int tlo, thi; arc_kr(a2, len2, tlo, thi);
      if (k0 == 0) tlo = 0;
      if (thi < KAc || tlo > KBc) continue;
    }
#pragma unroll
    for (int it = 0; it < 2; ++it) {
      gload_lds16(Ag + (size_t)(it * 64) * NN + k0, &As[wave * 512 + it * 2048]);
      gload_lds16(Bg + (size_t)(it * 64) * NN + k0, &Bs[wave * 512 + it * 2048]);
    }
    __syncthreads();

    bf16x8 af[4], bfr[4];
#pragma unroll
    for (int a_ = 0; a_ < 4; ++a_)
      af[a_] = *(const bf16x8*)&As[(wm * 64 + a_ * 16 + fm) * BK + kbr * 8];
#pragma unroll
    for (int b_ = 0; b_ < 4; ++b_)
      bfr[b_] = *(const bf16x8*)&Bs[(wn * 64 + b_ * 16 + fm) * BK + kbr * 8];
#pragma unroll
    for (int a_ = 0; a_ < 4; ++a_)
#pragma unroll
      for (int b_ = 0; b_ < 4; ++b_)
        acc[a_][b_] = __builtin_amdgcn_mfma_f32_16x16x32_bf16(af[a_], bfr[b_], acc[a_][b_], 0, 0, 0);
    __syncthreads();
  }

  const int row_in = (lane >> 4) * 4;
#pragma unroll
  for (int a_ = 0; a_ < 4; ++a_) {
#pragma unroll
    for (int b_ = 0; b_ < 4; ++b_) {
      const int gn = bn * BN + wn * 64 + b_ * 16 + fm;
#pragma unroll
      for (int v = 0; v < 4; ++v) {
        const int gm = bm * BM + wm * 64 + a_ * 16 + row_in + v;
        C[(size_t)gm * NN + gn] = f2bf(acc[a_][b_][v]);
      }
    }
  }
}

// ---- final: out = x_bf16 * U^T + bias (fp32 out). Verified rounds 1-14.
__global__ __launch_bounds__(256) void gemm_kernel(
    const unsigned short* __restrict__ A, const unsigned short* __restrict__ B,
    const float* __restrict__ bias, float* __restrict__ C) {
  __shared__ unsigned short As[BM * BK];
  __shared__ unsigned short Bs[BN * BK];
  const int tid  = threadIdx.x;
  const int lane = tid & 63;
  const int wave = tid >> 6;
  const int bm = blockIdx.x, bn = blockIdx.y;
  const int wm = wave & 1, wn = wave >> 1;

  const int srow = wave * 16 + (lane >> 2);
  const int scol = (lane & 3) * 8;
  const unsigned short* Ag = A + (size_t)(bm * BM + srow) * NN + scol;
  const unsigned short* Bg = B + (size_t)(bn * BN + srow) * NN + scol;

  const int fm = lane & 15;
  const int kbr = lane >> 4;

  f32x4 acc[4][4];
#pragma unroll
  for (int a_ = 0; a_ < 4; ++a_)
#pragma unroll
    for (int b_ = 0; b_ < 4; ++b_) acc[a_][b_] = (f32x4){0.f, 0.f, 0.f, 0.f};

  for (int kt = 0; kt < NN / BK; ++kt) {
    const int k0 = kt * BK;
#pragma unroll
    for (int it = 0; it < 2; ++it) {
      gload_lds16(Ag + (size_t)(it * 64) * NN + k0, &As[wave * 512 + it * 2048]);
      gload_lds16(Bg + (size_t)(it * 64) * NN + k0, &Bs[wave * 512 + it * 2048]);
    }
    __syncthreads();

    bf16x8 af[4], bfr[4];
#pragma unroll
    for (int a_ = 0; a_ < 4; ++a_)
      af[a_] = *(const bf16x8*)&As[(wm * 64 + a_ * 16 + fm) * BK + kbr * 8];
#pragma unroll
    for (int b_ = 0; b_ < 4; ++b_)
      bfr[b_] = *(const bf16x8*)&Bs[(wn * 64 + b_ * 16 + fm) * BK + kbr * 8];
#pragma unroll
    for (int a_ = 0; a_ < 4; ++a_)
#pragma unroll
      for (int b_ = 0; b_ < 4; ++b_)
        acc[a_][b_] = __builtin_amdgcn_mfma_f32_16x16x32_bf16(af[a_], bfr[b_], acc[a_][b_], 0, 0, 0);
    __syncthreads();
  }

  const int row_in = (lane >> 4) * 4;
#pragma unroll
  for (int a_ = 0; a_ < 4; ++a_) {
#pragma unroll
    for (int b_ = 0; b_ < 4; ++b_) {
      const int gn = bn * BN + wn * 64 + b_ * 16 + fm;
      const float bv = bias[gn];
#pragma unroll
      for (int v = 0; v < 4; ++v) {
        const int gm = bm * BM + wm * 64 + a_ * 16 + row_in + v;
        C[(size_t)gm * NN + gn] = acc[a_][b_][v] + bv;
      }
    }
  }
}

extern "C" void kernel_launch(void* const* d_in, const int* in_sizes, int n_in,
                              void* d_out, int out_size, void* d_ws, size_t ws_size,
                              hipStream_t stream) {
  const float* x      = (const float*)d_in[0];
  const float* angles = (const float*)d_in[1];
  const float* bias   = (const float*)d_in[2];
  float* out = (float*)d_out;

  char* ws = (char*)d_ws;
  unsigned short* P0  = (unsigned short*)(ws + 0);         //  8,388,608
  unsigned short* P1  = (unsigned short*)(ws + 8388608);   //  8,388,608
  char*           cs  = ws + 16777216;                     // 16,809,984 (2052 slices)
  unsigned short* B7  = (unsigned short*)(ws + 33587200);  //  8,388,608
  unsigned short* B8  = (unsigned short*)(ws + 41975808);  //  8,388,608 -> end 50,364,416
  unsigned short* xb  = (unsigned short*)(ws + 16777216);  // overlay (after comps)

  // B1..B6 live in d_out (67.1 MB; final gemm overwrites all of d_out at the end)
  char* ob = (char*)d_out;
  unsigned short* B1 = (unsigned short*)(ob + 0);
  unsigned short* B2 = (unsigned short*)(ob + 8388608);
  unsigned short* B3 = (unsigned short*)(ob + 16777216);
  unsigned short* B4 = (unsigned short*)(ob + 25165824);
  unsigned short* B5 = (unsigned short*)(ob + 33554432);
  unsigned short* B6 = (unsigned short*)(ob + 41943040);   // end 50,331,648 <= 67,108,864

  prep_kernel<<<dim3(8188), dim3(256), 0, stream>>>(angles, (float2*)cs);
  zero_kernel<<<dim3(2048), dim3(256), 0, stream>>>((uint4*)ob, 50331648 / 16);
  zero_kernel<<<dim3(1024), dim3(256), 0, stream>>>((uint4*)P0, 8388608 / 16);
  zero_kernel<<<dim3(1024), dim3(256), 0, stream>>>((uint4*)(ws + 33587200), 16777216 / 16);

  // single merged leaf dispatch, XCD-aligned: chunk = bid & 7 (one chunk per XCD)
  LeafOuts lo_main;
  lo_main.p[0] = P0; lo_main.p[1] = B1; lo_main.p[2] = B2; lo_main.p[3] = B3;
  lo_main.p[4] = B4; lo_main.p[5] = B5; lo_main.p[6] = B6; lo_main.p[7] = B7;
  leaf_kernel<254><<<dim3(2048), dim3(256), 0, stream>>>(cs, lo_main, 0, 1, 7, 3);
  // chunk 8 (15 steps)
  LeafOuts lo_tail;
  for (int i = 0; i < 8; ++i) lo_tail.p[i] = B8;
  leaf_kernel<15><<<dim3(256), dim3(256), 0, stream>>>(cs, lo_tail, 8, 0, 0, 0);

  // composition chain: P = B0 * B1 * ... * B8
  comp_kernel<<<dim3(16, 16), dim3(256), 0, stream>>>(P0, B1, P1,  254,  508);
  comp_kernel<<<dim3(16, 16), dim3(256), 0, stream>>>(P1, B2, P0,  508,  762);
  comp_kernel<<<dim3(16, 16), dim3(256), 0, stream>>>(P0, B3, P1,  762, 1016);
  comp_kernel<<<dim3(16, 16), dim3(256), 0, stream>>>(P1, B4, P0, 1016, 1270);
  comp_kernel<<<dim3(16, 16), dim3(256), 0, stream>>>(P0, B5, P1, 1270, 1524);
  comp_kernel<<<dim3(16, 16), dim3(256), 0, stream>>>(P1, B6, P0, 1524, 1778);
  comp_kernel<<<dim3(16, 16), dim3(256), 0, stream>>>(P0, B7, P1, 1778, 2032);
  comp_kernel<<<dim3(16, 16), dim3(256), 0, stream>>>(P1, B8, P0, 2032, 2047);

  // x -> bf16 into overlay (cs/B7/B8 dead now), then final GEMM overwrites d_out
  cvt_kernel<<<dim3(16384), dim3(256), 0, stream>>>((const float4*)x, (ushort4*)xb,
                                                    MROWS * NN / 4);
  gemm_kernel<<<dim3(MROWS / BM, NN / BN), dim3(256), 0, stream>>>(xb, P0, bias, out);
}

// Round 16
// 798.911 us; speedup vs baseline: 1.2077x; 1.0545x over previous
//
#include <hip/hip_runtime.h>
#include <hip/hip_bf16.h>

#define NN      2048
#define NSTEPS  2047
#define MROWS   8192
#define PADK    8

typedef __attribute__((ext_vector_type(8))) __bf16 bf16x8;
typedef __attribute__((ext_vector_type(4))) float  f32x4;
typedef __attribute__((ext_vector_type(2))) float  f32x2;

struct LeafOuts { unsigned short* p[8]; };

__device__ __forceinline__ unsigned short f2bf(float f) {
  unsigned int u = __float_as_uint(f);
  u += 0x7fffu + ((u >> 16) & 1u);   // RNE
  return (unsigned short)(u >> 16);
}

__device__ __forceinline__ void gload_lds16(const void* g, void* l) {
  __builtin_amdgcn_global_load_lds((const __attribute__((address_space(1))) void*)g,
                                   (__attribute__((address_space(3))) void*)l, 16, 0, 0);
}

// DPP wave-wide lane shifts (VALU pipe). Verified rounds 6-15.
template<int CTRL>
__device__ __forceinline__ float dppf(float v) {
  return __int_as_float(__builtin_amdgcn_update_dpp(
      __float_as_int(v), __float_as_int(v), CTRL, 0xf, 0xf, false));
}
#define DPP_UP 0x138
#define DPP_DN 0x130

// Packed fp32 rotation math. Verified rounds 7-15.
__device__ __forceinline__ f32x2 pk_smul(f32x2 cs, f32x2 v) {
  f32x2 d;
  asm("v_pk_mul_f32 %0, %1, %2 op_sel:[1,0] op_sel_hi:[1,1]"
      : "=v"(d) : "v"(cs), "v"(v));
  return d;
}
__device__ __forceinline__ f32x2 pk_cfma(f32x2 cs, f32x2 v, f32x2 a) {
  f32x2 d;
  asm("v_pk_fma_f32 %0, %1, %2, %3 op_sel:[0,0,0] op_sel_hi:[0,1,1]"
      : "=v"(d) : "v"(cs), "v"(v), "v"(a));
  return d;
}
__device__ __forceinline__ f32x2 pk_cfma_neg(f32x2 cs, f32x2 v, f32x2 a) {
  f32x2 d;
  asm("v_pk_fma_f32 %0, %1, %2, %3 op_sel:[0,0,0] op_sel_hi:[0,1,1] neg_lo:[0,0,1] neg_hi:[0,0,1]"
      : "=v"(d) : "v"(cs), "v"(v), "v"(a));
  return d;
}

// ---- angles -> (cos,sin), PLANE layout per 8KB slice (r15-verified):
// [plane(4)][entry(128)][b(2)] float2; pair p = 8*entry + 2*plane + b.
__global__ __launch_bounds__(256) void prep_kernel(
    const float* __restrict__ angles, float2* __restrict__ cs) {
  int t = blockIdx.x * 256 + threadIdx.x;
  if (t >= NSTEPS * 1024) return;
  const int slice = t >> 10;
  const int w     = t & 1023;
  const int plane = w >> 8;
  const int r     = w & 255;
  const int entry = r >> 1;
  const int b     = r & 1;
  const int p     = 8 * entry + 2 * plane + b;
  float s, c;
  sincosf(angles[slice * 1024 + p], &s, &c);
  cs[t] = make_float2(c, s);
}

// ---- x fp32 -> bf16
__global__ __launch_bounds__(256) void cvt_kernel(
    const float4* __restrict__ x, ushort4* __restrict__ xb, int n4) {
  int idx = blockIdx.x * 256 + threadIdx.x;
  if (idx >= n4) return;
  float4 v = x[idx];
  ushort4 o;
  o.x = f2bf(v.x); o.y = f2bf(v.y); o.z = f2bf(v.z); o.w = f2bf(v.w);
  xb[idx] = o;
}

// ---- zero scratch region (grid-stride)
__global__ __launch_bounds__(256) void zero_kernel(uint4* __restrict__ p, int n) {
  int idx = blockIdx.x * 256 + threadIdx.x;
  const int stride = gridDim.x * 256;
  const uint4 z = make_uint4(0, 0, 0, 0);
  for (; idx < n; idx += stride) p[idx] = z;
}

// ---- leaf: build chunk matrix B_c rows by windowed wave-autonomous conveyor.
// LC==254: TRIANGULAR two-phase window — phase A (T=0..123) P=4 over a 256-window
// (support cone fits: width 2T+2 <= 250), one-time shuffle transition at T=124
// (chosen 0 mod 4 / 4 mod 8 for clean register phases), phase B (T=124..253)
// = r15-verified P=8 machinery. Other LC: r15 plain path.
template<int LC>
__global__ __launch_bounds__(256) void leaf_kernel(
    const char* __restrict__ csb, LeafOuts outs, int c_base, int first_rm,
    int cmask, int cshift) {
  const int tid  = threadIdx.x;
  const int lane = tid & 63;
  const int cl   = blockIdx.x & cmask;
  const int v    = ((blockIdx.x >> cshift) << 2) + (tid >> 6);
  const int c    = c_base + cl;
  const int t0   = 254 * c;
  unsigned short* out = outs.p[cl];
  const bool rm = (first_rm != 0) && (cl == 0);

  const int pA = 2 * v, pB = 2 * v + 1;
  const int kA = (pA <= 1023) ? pA : 2047 - pA;
  const int kBp = (pB <= 1023) ? pB : 2047 - pB;
  const int kmin = min(kA, kBp);
  int kb = (kmin - 254) & ~1;
  kb = min(max(kb, 0), 512);
  const bool l0 = (lane == 0), l63 = (lane == 63);
  const bool c0l0  = (kb == 0)   && l0;
  const bool cTl63 = (kb == 512) && l63;

  f32x2 FF[8], SS[8];

#define CP(CV, K) (((const f32x2*)&(CV))[(K)])

#define ROTE(E, CPp) { \
    const int rF = ((E) - PHI) & 7, rS = ((E) + PHI) & 7; \
    const f32x2 cp_ = (CPp); \
    const f32x2 t_ = pk_smul(cp_, SS[rS]); \
    const f32x2 u_ = pk_smul(cp_, FF[rF]); \
    FF[rF] = pk_cfma(cp_, FF[rF], t_); \
    SS[rS] = pk_cfma_neg(cp_, SS[rS], u_); }

#define LSTEP(PHI_, C0, C1, C2, C3, GP) { \
    const int PHI = (PHI_); \
    const int pF = (7 - PHI) & 7, pT = (8 - PHI) & 7; \
    ROTE(0, CP(C0, 0)) ROTE(1, CP(C0, 1)) \
    ROTE(2, CP(C1, 0)) ROTE(3, CP(C1, 1)) \
    ROTE(4, CP(C2, 0)) ROTE(5, CP(C2, 1)) \
    ROTE(6, CP(C3, 0)) ROTE(7, CP(C3, 1)) \
    const f32x2 Fo = FF[pF], So = SS[PHI], St = FF[pT]; \
    f32x2 fi, sd; \
    fi.x = dppf<DPP_UP>(Fo.x); fi.y = dppf<DPP_UP>(Fo.y); \
    sd.x = dppf<DPP_DN>(So.x); sd.y = dppf<DPP_DN>(So.y); \
    C0 = *(const float4*)GP[0]; C1 = *(const float4*)GP[1]; \
    C2 = *(const float4*)GP[2]; C3 = *(const float4*)GP[3]; \
    GP[0] += 16384; GP[1] += 16384; GP[2] += 16384; GP[3] += 16384; \
    const f32x2 z2 = {0.f, 0.f}; \
    const f32x2 xF = c0l0 ? St : z2; \
    const f32x2 xS = cTl63 ? Fo : z2; \
    FF[pF]  = l0  ? xF : fi; \
    SS[PHI] = l63 ? xS : sd; \
    FF[pT]  = c0l0 ? So : FF[pT]; \
  }

  if constexpr (LC == 254) {
    // ---------- phase A: T = 0..123, window [kb2, kb2+255], 4 pairs/lane ----------
    const int kb2 = min(max((kmin - 124) & ~1, 0), 768);
    const bool a0l0  = (kb2 == 0)   && l0;
    const bool aTl63 = (kb2 == 768) && l63;

#pragma unroll
    for (int e = 0; e < 4; ++e) {
      const int k = kb2 + 4 * lane + e, m = 2047 - k;
      FF[e] = (f32x2){(k == pA) ? 1.f : 0.f, (k == pB) ? 1.f : 0.f};
      SS[e] = (f32x2){(m == pA) ? 1.f : 0.f, (m == pB) ? 1.f : 0.f};
    }

    // A cs addressing: lane's pairs P0..P0+3 (P0 = kb2+4*lane) = 2x 16B groups
    // group g at plane (u&3), entry (u>>2) with u = (kb2>>1) + 2*lane + g.
    const int ub = (kb2 >> 1) + 2 * lane;
    const char* csq = csb + (size_t)t0 * 8192;
    const char* aE0 = csq + ((ub & 3) * 2048 + (ub >> 2) * 16);
    const char* aE1 = csq + ((((ub + 1) & 3)) * 2048 + ((ub + 1) >> 2) * 16);
    const char* aO0 = aE0 + 8192;
    const char* aO1 = aE1 + 8192;
    float4 A0E = *(const float4*)aE0, A1E = *(const float4*)aE1;   // slice 0
    float4 A0O = *(const float4*)aO0, A1O = *(const float4*)aO1;   // slice 1
    aE0 += 16384; aE1 += 16384; aO0 += 16384; aO1 += 16384;        // -> 2,3

#define ROTE4(E, CPp) { \
    const int rF = ((E) - PHI) & 3, rS = ((E) + PHI) & 3; \
    const f32x2 cp_ = (CPp); \
    const f32x2 t_ = pk_smul(cp_, SS[rS]); \
    const f32x2 u_ = pk_smul(cp_, FF[rF]); \
    FF[rF] = pk_cfma(cp_, FF[rF], t_); \
    SS[rS] = pk_cfma_neg(cp_, SS[rS], u_); }

#define ASTEP(PHI_, C0, C1, GP0, GP1) { \
    const int PHI = (PHI_); \
    const int pF = (3 - PHI) & 3, pT = (4 - PHI) & 3; \
    ROTE4(0, CP(C0, 0)) ROTE4(1, CP(C0, 1)) \
    ROTE4(2, CP(C1, 0)) ROTE4(3, CP(C1, 1)) \
    const f32x2 Fo = FF[pF], So = SS[PHI], St = FF[pT]; \
    f32x2 fi, sd; \
    fi.x = dppf<DPP_UP>(Fo.x); fi.y = dppf<DPP_UP>(Fo.y); \
    sd.x = dppf<DPP_DN>(So.x); sd.y = dppf<DPP_DN>(So.y); \
    C0 = *(const float4*)GP0; C1 = *(const float4*)GP1; \
    GP0 += 16384; GP1 += 16384; \
    const f32x2 z2 = {0.f, 0.f}; \
    const f32x2 xF = a0l0 ? St : z2; \
    const f32x2 xS = aTl63 ? Fo : z2; \
    FF[pF]  = l0  ? xF : fi; \
    SS[PHI] = l63 ? xS : sd; \
    FF[pT]  = a0l0 ? So : FF[pT]; \
  }

#pragma unroll 1
    for (int it = 0; it < 31; ++it) {
      ASTEP(0, A0E, A1E, aE0, aE1)
      ASTEP(1, A0O, A1O, aO0, aO1)
      ASTEP(2, A0E, A1E, aE0, aE1)
      ASTEP(3, A0O, A1O, aO0, aO1)
    }

    // ---------- transition at T = 124 ----------
    // A regs: F elem j in FF[j&3], S elem j in SS[j&3] (124 % 4 == 0).
    // New pair q = kb+8*lane+e: d = q-kb2; src lane d>>2, src reg (e-dlt)&3.
    // Commit to B mapping at T=124: F elem e -> FF[(e+4)&7], S -> SS[(e+4)&7].
    {
      const int dlt = kb2 - kb;               // even, >= 0
      const int base_d = 8 * lane - dlt;
      f32x2 nF[8], nS[8];

#define TGETF(E, SR) { \
      const int d_ = base_d + (E); \
      const int sl_ = (d_ >> 2) & 63; \
      f32x2 fv_; \
      fv_.x = __shfl(FF[SR].x, sl_); \
      fv_.y = __shfl(FF[SR].y, sl_); \
      nF[E] = ((unsigned)d_ < 256u) ? fv_ : (f32x2){0.f, 0.f}; }
#define TGETS(E, SR) { \
      const int d_ = base_d + (E); \
      const int sl_ = (d_ >> 2) & 63; \
      f32x2 sv_; \
      sv_.x = __shfl(SS[SR].x, sl_); \
      sv_.y = __shfl(SS[SR].y, sl_); \
      nS[E] = ((unsigned)d_ < 256u) ? sv_ : (f32x2){0.f, 0.f}; }

      if ((dlt & 3) == 0) {
        TGETF(0,0) TGETF(1,1) TGETF(2,2) TGETF(3,3)
        TGETF(4,0) TGETF(5,1) TGETF(6,2) TGETF(7,3)
      } else {
        TGETF(0,2) TGETF(1,3) TGETF(2,0) TGETF(3,1)
        TGETF(4,2) TGETF(5,3) TGETF(6,0) TGETF(7,1)
      }
      FF[4] = nF[0]; FF[5] = nF[1]; FF[6] = nF[2]; FF[7] = nF[3];
      FF[0] = nF[4]; FF[1] = nF[5]; FF[2] = nF[6]; FF[3] = nF[7];
      if ((dlt & 3) == 0) {
        TGETS(0,0) TGETS(1,1) TGETS(2,2) TGETS(3,3)
        TGETS(4,0) TGETS(5,1) TGETS(6,2) TGETS(7,3)
      } else {
        TGETS(0,2) TGETS(1,3) TGETS(2,0) TGETS(3,1)
        TGETS(4,2) TGETS(5,3) TGETS(6,0) TGETS(7,1)
      }
      SS[4] = nS[0]; SS[5] = nS[1]; SS[6] = nS[2]; SS[7] = nS[3];
      SS[0] = nS[4]; SS[1] = nS[5]; SS[2] = nS[6]; SS[3] = nS[7];
    }

    // ---------- phase B: T = 124..253, r15 machinery ----------
    const int kb8 = kb >> 3, mm = (kb >> 1) & 3;
    const char* basep = csb + (size_t)t0 * 8192 + 16 * lane + (size_t)124 * 8192;
    const char* gE[4];
    const char* gO[4];
#pragma unroll
    for (int ep = 0; ep < 4; ++ep) {
      const int u = mm + ep;
      const int off = (u & 3) * 2048 + (kb8 + (u >> 2)) * 16;
      gE[ep] = basep + off;
      gO[ep] = basep + off + 8192;
    }
    float4 cE0 = *(const float4*)gE[0], cE1 = *(const float4*)gE[1];
    float4 cE2 = *(const float4*)gE[2], cE3 = *(const float4*)gE[3];   // slice 124
    float4 cO0 = *(const float4*)gO[0], cO1 = *(const float4*)gO[1];
    float4 cO2 = *(const float4*)gO[2], cO3 = *(const float4*)gO[3];   // slice 125
#pragma unroll
    for (int ep = 0; ep < 4; ++ep) { gE[ep] += 16384; gO[ep] += 16384; }

    LSTEP(4, cE0, cE1, cE2, cE3, gE)
    LSTEP(5, cO0, cO1, cO2, cO3, gO)
    LSTEP(6, cE0, cE1, cE2, cE3, gE)
    LSTEP(7, cO0, cO1, cO2, cO3, gO)
#pragma unroll 1
    for (int it = 0; it < 15; ++it) {
      LSTEP(0, cE0, cE1, cE2, cE3, gE)
      LSTEP(1, cO0, cO1, cO2, cO3, gO)
      LSTEP(2, cE0, cE1, cE2, cE3, gE)
      LSTEP(3, cO0, cO1, cO2, cO3, gO)
      LSTEP(4, cE0, cE1, cE2, cE3, gE)
      LSTEP(5, cO0, cO1, cO2, cO3, gO)
      LSTEP(6, cE0, cE1, cE2, cE3, gE)
      LSTEP(7, cO0, cO1, cO2, cO3, gO)
    }
    LSTEP(0, cE0, cE1, cE2, cE3, gE)
    LSTEP(1, cO0, cO1, cO2, cO3, gO)
    LSTEP(2, cE0, cE1, cE2, cE3, gE)
    LSTEP(3, cO0, cO1, cO2, cO3, gO)
    LSTEP(4, cE0, cE1, cE2, cE3, gE)
    LSTEP(5, cO0, cO1, cO2, cO3, gO)
  } else {
    // ---------- plain path (LC = 15): r15 verbatim ----------
#pragma unroll
    for (int e = 0; e < 8; ++e) {
      const int k = kb + 8 * lane + e, m = 2047 - k;
      FF[e] = (f32x2){(k == pA) ? 1.f : 0.f, (k == pB) ? 1.f : 0.f};
      SS[e] = (f32x2){(m == pA) ? 1.f : 0.f, (m == pB) ? 1.f : 0.f};
    }
    const int kb8 = kb >> 3, mm = (kb >> 1) & 3;
    const char* basep = csb + (size_t)t0 * 8192 + 16 * lane;
    const char* gE[4];
    const char* gO[4];
#pragma unroll
    for (int ep = 0; ep < 4; ++ep) {
      const int u = mm + ep;
      const int off = (u & 3) * 2048 + (kb8 + (u >> 2)) * 16;
      gE[ep] = basep + off;
      gO[ep] = basep + off + 8192;
    }
    float4 cE0 = *(const float4*)gE[0], cE1 = *(const float4*)gE[1];
    float4 cE2 = *(const float4*)gE[2], cE3 = *(const float4*)gE[3];
    float4 cO0 = *(const float4*)gO[0], cO1 = *(const float4*)gO[1];
    float4 cO2 = *(const float4*)gO[2], cO3 = *(const float4*)gO[3];
#pragma unroll
    for (int ep = 0; ep < 4; ++ep) { gE[ep] += 16384; gO[ep] += 16384; }

    constexpr int ITERS = LC / 8;
    constexpr int TAIL  = LC & 7;
#pragma unroll 1
    for (int it = 0; it < ITERS; ++it) {
      LSTEP(0, cE0, cE1, cE2, cE3, gE)
      LSTEP(1, cO0, cO1, cO2, cO3, gO)
      LSTEP(2, cE0, cE1, cE2, cE3, gE)
      LSTEP(3, cO0, cO1, cO2, cO3, gO)
      LSTEP(4, cE0, cE1, cE2, cE3, gE)
      LSTEP(5, cO0, cO1, cO2, cO3, gO)
      LSTEP(6, cE0, cE1, cE2, cE3, gE)
      LSTEP(7, cO0, cO1, cO2, cO3, gO)
    }
    if constexpr (TAIL >= 1) LSTEP(0, cE0, cE1, cE2, cE3, gE)
    if constexpr (TAIL >= 2) LSTEP(1, cO0, cO1, cO2, cO3, gO)
    if constexpr (TAIL >= 3) LSTEP(2, cE0, cE1, cE2, cE3, gE)
    if constexpr (TAIL >= 4) LSTEP(3, cO0, cO1, cO2, cO3, gO)
    if constexpr (TAIL >= 5) LSTEP(4, cE0, cE1, cE2, cE3, gE)
    if constexpr (TAIL >= 6) LSTEP(5, cO0, cO1, cO2, cO3, gO)
    if constexpr (TAIL >= 7) LSTEP(6, cE0, cE1, cE2, cE3, gE)
  }

  // readout at T=LC: F elem e in FF[(e-LC)&7]; S elem e in SS[(e+LC)&7].
  constexpr int RPH = LC & 7;
  const int tend = t0 + LC;
  const int rA = (pA == 0) ? 0 : ((pA - 1 - t0 + 4094) % 2047) + 1;
  const int rB = ((pB - 1 - t0 + 4094) % 2047) + 1;
#pragma unroll
  for (int e = 0; e < 8; ++e) {
    const int k = kb + 8 * lane + e;
    const int lF = (k == 0) ? 0 : ((k - 1 - tend + 4094) % 2047) + 1;
    const int lS = ((2046 - k - tend + 4094) % 2047) + 1;
    const f32x2 fv = FF[(e - RPH) & 7];
    const f32x2 sv = SS[(e + RPH) & 7];
    if (rm) {
      out[(size_t)rA * NN + lF] = f2bf(fv.x);
      out[(size_t)rB * NN + lF] = f2bf(fv.y);
      out[(size_t)rA * NN + lS] = f2bf(sv.x);
      out[(size_t)rB * NN + lS] = f2bf(sv.y);
    } else {
      out[(size_t)lF * NN + rA] = f2bf(fv.x);
      out[(size_t)lF * NN + rB] = f2bf(fv.y);
      out[(size_t)lS * NN + rA] = f2bf(sv.x);
      out[(size_t)lS * NN + rB] = f2bf(sv.y);
    }
  }
}

// κ-range of a cyclic position arc [a, a+len-1] in [1..2047], κ(p)=min(p,2047-p)
__device__ __forceinline__ void arc_kr(int a, int len, int& lo, int& hi) {
  int last = a + len - 1; if (last > 2047) last -= 2047;
  const int k1 = min(a, 2047 - a), k2 = min(last, 2047 - last);
  lo = min(k1, k2); hi = max(k1, k2);
  int d;
  d = 1023 - a; if (d < 0) d += 2047; if (d < len) hi = 1023;
  d = 1024 - a; if (d < 0) d += 2047; if (d < len) hi = 1023;
  d = 2047 - a; if (d < 0) d += 2047; if (d < len) lo = 0;
  d = 1    - a; if (d < 0) d += 2047; if (d < len) lo = min(lo, 1);
}

#define BM 128
#define BN 128
#define BK 32

// ---- comp: C = A * Bt^T (2048^3), bf16 out, K-tiles band-skipped by cone test.
__global__ __launch_bounds__(256) void comp_kernel(
    const unsigned short* __restrict__ A, const unsigned short* __restrict__ B,
    unsigned short* __restrict__ C, int ta, int tb) {
  __shared__ unsigned short As[BM * BK];
  __shared__ unsigned short Bs[BN * BK];
  const int tid  = threadIdx.x;
  const int lane = tid & 63;
  const int wave = tid >> 6;
  const int bm = blockIdx.x, bn = blockIdx.y;
  const int wm = wave & 1, wn = wave >> 1;

  const int n0 = bn * BN;
  int qlo, qhi;
  {
    const int nfirst = (n0 == 0) ? 1 : n0;
    const int a = ((nfirst - 1 + tb) % 2047) + 1;
    const int len = (n0 == 0) ? (BN - 1) : BN;
    arc_kr(a, len, qlo, qhi);
    if (n0 == 0) qlo = 0;
  }
  const int L = tb - ta;
  const int KAc = max(qlo - L - PADK, 0);
  const int KBc = min(qhi + L + PADK, 1023);

  const int srow = wave * 16 + (lane >> 2);
  const int scol = (lane & 3) * 8;
  const unsigned short* Ag = A + (size_t)(bm * BM + srow) * NN + scol;
  const unsigned short* Bg = B + (size_t)(bn * BN + srow) * NN + scol;

  const int fm = lane & 15;
  const int kbr = lane >> 4;

  f32x4 acc[4][4];
#pragma unroll
  for (int a_ = 0; a_ < 4; ++a_)
#pragma unroll
    for (int b_ = 0; b_ < 4; ++b_) acc[a_][b_] = (f32x4){0.f, 0.f, 0.f, 0.f};

  for (int kt = 0; kt < NN / BK; ++kt) {
    const int k0 = kt * BK;
    {
      const int kfirst = (k0 == 0) ? 1 : k0;
      const int a2 = ((kfirst - 1 + ta) % 2047) + 1;
      const int len2 = (k0 == 0) ? (BK - 1) : BK;
      int tlo, thi; arc_kr(a2, len2, tlo, thi);
      if (k0 == 0) tlo = 0;
      if (thi < KAc || tlo > KBc) continue;
    }
#pragma unroll
    for (int it = 0; it < 2; ++it) {
      gload_lds16(Ag + (size_t)(it * 64) * NN + k0, &As[wave * 512 + it * 2048]);
      gload_lds16(Bg + (size_t)(it * 64) * NN + k0, &Bs[wave * 512 + it * 2048]);
    }
    __syncthreads();

    bf16x8 af[4], bfr[4];
#pragma unroll
    for (int a_ = 0; a_ < 4; ++a_)
      af[a_] = *(const bf16x8*)&As[(wm * 64 + a_ * 16 + fm) * BK + kbr * 8];
#pragma unroll
    for (int b_ = 0; b_ < 4; ++b_)
      bfr[b_] = *(const bf16x8*)&Bs[(wn * 64 + b_ * 16 + fm) * BK + kbr * 8];
#pragma unroll
    for (int a_ = 0; a_ < 4; ++a_)
#pragma unroll
      for (int b_ = 0; b_ < 4; ++b_)
        acc[a_][b_] = __builtin_amdgcn_mfma_f32_16x16x32_bf16(af[a_], bfr[b_], acc[a_][b_], 0, 0, 0);
    __syncthreads();
  }

  const int row_in = (lane >> 4) * 4;
#pragma unroll
  for (int a_ = 0; a_ < 4; ++a_) {
#pragma unroll
    for (int b_ = 0; b_ < 4; ++b_) {
      const int gn = bn * BN + wn * 64 + b_ * 16 + fm;
#pragma unroll
      for (int v = 0; v < 4; ++v) {
        const int gm = bm * BM + wm * 64 + a_ * 16 + row_in + v;
        C[(size_t)gm * NN + gn] = f2bf(acc[a_][b_][v]);
      }
    }
  }
}

// ---- final: out = x_bf16 * U^T + bias (fp32 out). Verified rounds 1-15.
__global__ __launch_bounds__(256) void gemm_kernel(
    const unsigned short* __restrict__ A, const unsigned short* __restrict__ B,
    const float* __restrict__ bias, float* __restrict__ C) {
  __shared__ unsigned short As[BM * BK];
  __shared__ unsigned short Bs[BN * BK];
  const int tid  = threadIdx.x;
  const int lane = tid & 63;
  const int wave = tid >> 6;
  const int bm = blockIdx.x, bn = blockIdx.y;
  const int wm = wave & 1, wn = wave >> 1;

  const int srow = wave * 16 + (lane >> 2);
  const int scol = (lane & 3) * 8;
  const unsigned short* Ag = A + (size_t)(bm * BM + srow) * NN + scol;
  const unsigned short* Bg = B + (size_t)(bn * BN + srow) * NN + scol;

  const int fm = lane & 15;
  const int kbr = lane >> 4;

  f32x4 acc[4][4];
#pragma unroll
  for (int a_ = 0; a_ < 4; ++a_)
#pragma unroll
    for (int b_ = 0; b_ < 4; ++b_) acc[a_][b_] = (f32x4){0.f, 0.f, 0.f, 0.f};

  for (int kt = 0; kt < NN / BK; ++kt) {
    const int k0 = kt * BK;
#pragma unroll
    for (int it = 0; it < 2; ++it) {
      gload_lds16(Ag + (size_t)(it * 64) * NN + k0, &As[wave * 512 + it * 2048]);
      gload_lds16(Bg + (size_t)(it * 64) * NN + k0, &Bs[wave * 512 + it * 2048]);
    }
    __syncthreads();

    bf16x8 af[4], bfr[4];
#pragma unroll
    for (int a_ = 0; a_ < 4; ++a_)
      af[a_] = *(const bf16x8*)&As[(wm * 64 + a_ * 16 + fm) * BK + kbr * 8];
#pragma unroll
    for (int b_ = 0; b_ < 4; ++b_)
      bfr[b_] = *(const bf16x8*)&Bs[(wn * 64 + b_ * 16 + fm) * BK + kbr * 8];
#pragma unroll
    for (int a_ = 0; a_ < 4; ++a_)
#pragma unroll
      for (int b_ = 0; b_ < 4; ++b_)
        acc[a_][b_] = __builtin_amdgcn_mfma_f32_16x16x32_bf16(af[a_], bfr[b_], acc[a_][b_], 0, 0, 0);
    __syncthreads();
  }

  const int row_in = (lane >> 4) * 4;
#pragma unroll
  for (int a_ = 0; a_ < 4; ++a_) {
#pragma unroll
    for (int b_ = 0; b_ < 4; ++b_) {
      const int gn = bn * BN + wn * 64 + b_ * 16 + fm;
      const float bv = bias[gn];
#pragma unroll
      for (int v = 0; v < 4; ++v) {
        const int gm = bm * BM + wm * 64 + a_ * 16 + row_in + v;
        C[(size_t)gm * NN + gn] = acc[a_][b_][v] + bv;
      }
    }
  }
}

extern "C" void kernel_launch(void* const* d_in, const int* in_sizes, int n_in,
                              void* d_out, int out_size, void* d_ws, size_t ws_size,
                              hipStream_t stream) {
  const float* x      = (const float*)d_in[0];
  const float* angles = (const float*)d_in[1];
  const float* bias   = (const float*)d_in[2];
  float* out = (float*)d_out;

  char* ws = (char*)d_ws;
  unsigned short* P0  = (unsigned short*)(ws + 0);         //  8,388,608
  unsigned short* P1  = (unsigned short*)(ws + 8388608);   //  8,388,608
  char*           cs  = ws + 16777216;                     // 16,809,984 (2052 slices)
  unsigned short* B7  = (unsigned short*)(ws + 33587200);  //  8,388,608
  unsigned short* B8  = (unsigned short*)(ws + 41975808);  //  8,388,608 -> end 50,364,416
  unsigned short* xb  = (unsigned short*)(ws + 16777216);  // overlay (after comps)

  // B1..B6 live in d_out (67.1 MB; final gemm overwrites all of d_out at the end)
  char* ob = (char*)d_out;
  unsigned short* B1 = (unsigned short*)(ob + 0);
  unsigned short* B2 = (unsigned short*)(ob + 8388608);
  unsigned short* B3 = (unsigned short*)(ob + 16777216);
  unsigned short* B4 = (unsigned short*)(ob + 25165824);
  unsigned short* B5 = (unsigned short*)(ob + 33554432);
  unsigned short* B6 = (unsigned short*)(ob + 41943040);   // end 50,331,648 <= 67,108,864

  prep_kernel<<<dim3(8188), dim3(256), 0, stream>>>(angles, (float2*)cs);
  zero_kernel<<<dim3(2048), dim3(256), 0, stream>>>((uint4*)ob, 50331648 / 16);
  zero_kernel<<<dim3(1024), dim3(256), 0, stream>>>((uint4*)P0, 8388608 / 16);
  zero_kernel<<<dim3(1024), dim3(256), 0, stream>>>((uint4*)(ws + 33587200), 16777216 / 16);

  // single merged leaf dispatch, XCD-aligned: chunk = bid & 7 (one chunk per XCD)
  LeafOuts lo_main;
  lo_main.p[0] = P0; lo_main.p[1] = B1; lo_main.p[2] = B2; lo_main.p[3] = B3;
  lo_main.p[4] = B4; lo_main.p[5] = B5; lo_main.p[6] = B6; lo_main.p[7] = B7;
  leaf_kernel<254><<<dim3(2048), dim3(256), 0, stream>>>(cs, lo_main, 0, 1, 7, 3);
  // chunk 8 (15 steps)
  LeafOuts lo_tail;
  for (int i = 0; i < 8; ++i) lo_tail.p[i] = B8;
  leaf_kernel<15><<<dim3(256), dim3(256), 0, stream>>>(cs, lo_tail, 8, 0, 0, 0);

  // composition chain: P = B0 * B1 * ... * B8
  comp_kernel<<<dim3(16, 16), dim3(256), 0, stream>>>(P0, B1, P1,  254,  508);
  comp_kernel<<<dim3(16, 16), dim3(256), 0, stream>>>(P1, B2, P0,  508,  762);
  comp_kernel<<<dim3(16, 16), dim3(256), 0, stream>>>(P0, B3, P1,  762, 1016);
  comp_kernel<<<dim3(16, 16), dim3(256), 0, stream>>>(P1, B4, P0, 1016, 1270);
  comp_kernel<<<dim3(16, 16), dim3(256), 0, stream>>>(P0, B5, P1, 1270, 1524);
  comp_kernel<<<dim3(16, 16), dim3(256), 0, stream>>>(P1, B6, P0, 1524, 1778);
  comp_kernel<<<dim3(16, 16), dim3(256), 0, stream>>>(P0, B7, P1, 1778, 2032);
  comp_kernel<<<dim3(16, 16), dim3(256), 0, stream>>>(P1, B8, P0, 2032, 2047);

  // x -> bf16 into overlay (cs/B7/B8 dead now), then final GEMM overwrites d_out
  cvt_kernel<<<dim3(16384), dim3(256), 0, stream>>>((const float4*)x, (ushort4*)xb,
                                                    MROWS * NN / 4);
  gemm_kernel<<<dim3(MROWS / BM, NN / BN), dim3(256), 0, stream>>>(xb, P0, bias, out);
}

// Round 17
// 716.659 us; speedup vs baseline: 1.3463x; 1.1148x over previous
//
#include <hip/hip_runtime.h>
#include <hip/hip_bf16.h>

#define NN      2048
#define NSTEPS  2047
#define MROWS   8192
#define PADK    8

typedef __attribute__((ext_vector_type(8))) __bf16 bf16x8;
typedef __attribute__((ext_vector_type(4))) float  f32x4;
typedef __attribute__((ext_vector_type(2))) float  f32x2;

struct LeafOuts { unsigned short* p[8]; };

__device__ __forceinline__ unsigned short f2bf(float f) {
  unsigned int u = __float_as_uint(f);
  u += 0x7fffu + ((u >> 16) & 1u);   // RNE
  return (unsigned short)(u >> 16);
}

__device__ __forceinline__ void gload_lds16(const void* g, void* l) {
  __builtin_amdgcn_global_load_lds((const __attribute__((address_space(1))) void*)g,
                                   (__attribute__((address_space(3))) void*)l, 16, 0, 0);
}

// DPP wave-wide lane shifts (VALU pipe). Verified rounds 6-16.
template<int CTRL>
__device__ __forceinline__ float dppf(float v) {
  return __int_as_float(__builtin_amdgcn_update_dpp(
      __float_as_int(v), __float_as_int(v), CTRL, 0xf, 0xf, false));
}
#define DPP_UP 0x138
#define DPP_DN 0x130

// Packed fp32 rotation math. Verified rounds 7-16.
__device__ __forceinline__ f32x2 pk_smul(f32x2 cs, f32x2 v) {
  f32x2 d;
  asm("v_pk_mul_f32 %0, %1, %2 op_sel:[1,0] op_sel_hi:[1,1]"
      : "=v"(d) : "v"(cs), "v"(v));
  return d;
}
__device__ __forceinline__ f32x2 pk_cfma(f32x2 cs, f32x2 v, f32x2 a) {
  f32x2 d;
  asm("v_pk_fma_f32 %0, %1, %2, %3 op_sel:[0,0,0] op_sel_hi:[0,1,1]"
      : "=v"(d) : "v"(cs), "v"(v), "v"(a));
  return d;
}
__device__ __forceinline__ f32x2 pk_cfma_neg(f32x2 cs, f32x2 v, f32x2 a) {
  f32x2 d;
  asm("v_pk_fma_f32 %0, %1, %2, %3 op_sel:[0,0,0] op_sel_hi:[0,1,1] neg_lo:[0,0,1] neg_hi:[0,0,1]"
      : "=v"(d) : "v"(cs), "v"(v), "v"(a));
  return d;
}

// ---- angles -> (cos,sin), PLANE layout per 8KB slice (r15-verified):
// [plane(4)][entry(128)][b(2)] float2; pair p = 8*entry + 2*plane + b.
__global__ __launch_bounds__(256) void prep_kernel(
    const float* __restrict__ angles, float2* __restrict__ cs) {
  int t = blockIdx.x * 256 + threadIdx.x;
  if (t >= NSTEPS * 1024) return;
  const int slice = t >> 10;
  const int w     = t & 1023;
  const int plane = w >> 8;
  const int r     = w & 255;
  const int entry = r >> 1;
  const int b     = r & 1;
  const int p     = 8 * entry + 2 * plane + b;
  float s, c;
  sincosf(angles[slice * 1024 + p], &s, &c);
  cs[t] = make_float2(c, s);
}

// ---- x fp32 -> bf16
__global__ __launch_bounds__(256) void cvt_kernel(
    const float4* __restrict__ x, ushort4* __restrict__ xb, int n4) {
  int idx = blockIdx.x * 256 + threadIdx.x;
  if (idx >= n4) return;
  float4 v = x[idx];
  ushort4 o;
  o.x = f2bf(v.x); o.y = f2bf(v.y); o.z = f2bf(v.z); o.w = f2bf(v.w);
  xb[idx] = o;
}

// ---- zero scratch region (grid-stride)
__global__ __launch_bounds__(256) void zero_kernel(uint4* __restrict__ p, int n) {
  int idx = blockIdx.x * 256 + threadIdx.x;
  const int stride = gridDim.x * 256;
  const uint4 z = make_uint4(0, 0, 0, 0);
  for (; idx < n; idx += stride) p[idx] = z;
}

// ---- leaf: triangular two-phase windowed conveyor (r16-verified math).
// This round: SADDR addressing — step-invariant per-lane u32 offsets + scalar
// (wave-uniform) base pointers bumped on SALU. Same addresses, fewer VGPRs.
template<int LC>
__global__ __launch_bounds__(256) void leaf_kernel(
    const char* __restrict__ csb, LeafOuts outs, int c_base, int first_rm,
    int cmask, int cshift) {
  const int tid  = threadIdx.x;
  const int lane = tid & 63;
  const int cl   = blockIdx.x & cmask;
  const int v    = ((blockIdx.x >> cshift) << 2) + (tid >> 6);
  const int c    = c_base + cl;
  const int t0   = 254 * c;
  unsigned short* out = outs.p[cl];
  const bool rm = (first_rm != 0) && (cl == 0);

  const int pA = 2 * v, pB = 2 * v + 1;
  const int kA = (pA <= 1023) ? pA : 2047 - pA;
  const int kBp = (pB <= 1023) ? pB : 2047 - pB;
  const int kmin = min(kA, kBp);
  int kb = (kmin - 254) & ~1;
  kb = min(max(kb, 0), 512);
  const bool l0 = (lane == 0), l63 = (lane == 63);
  const bool c0l0  = (kb == 0)   && l0;
  const bool cTl63 = (kb == 512) && l63;

  f32x2 FF[8], SS[8];

#define CP(CV, K) (((const f32x2*)&(CV))[(K)])

#define ROTE(E, CPp) { \
    const int rF = ((E) - PHI) & 7, rS = ((E) + PHI) & 7; \
    const f32x2 cp_ = (CPp); \
    const f32x2 t_ = pk_smul(cp_, SS[rS]); \
    const f32x2 u_ = pk_smul(cp_, FF[rF]); \
    FF[rF] = pk_cfma(cp_, FF[rF], t_); \
    SS[rS] = pk_cfma_neg(cp_, SS[rS], u_); }

#define LSTEP(PHI_, C0, C1, C2, C3, BASE) { \
    const int PHI = (PHI_); \
    const int pF = (7 - PHI) & 7, pT = (8 - PHI) & 7; \
    ROTE(0, CP(C0, 0)) ROTE(1, CP(C0, 1)) \
    ROTE(2, CP(C1, 0)) ROTE(3, CP(C1, 1)) \
    ROTE(4, CP(C2, 0)) ROTE(5, CP(C2, 1)) \
    ROTE(6, CP(C3, 0)) ROTE(7, CP(C3, 1)) \
    const f32x2 Fo = FF[pF], So = SS[PHI], St = FF[pT]; \
    f32x2 fi, sd; \
    fi.x = dppf<DPP_UP>(Fo.x); fi.y = dppf<DPP_UP>(Fo.y); \
    sd.x = dppf<DPP_DN>(So.x); sd.y = dppf<DPP_DN>(So.y); \
    C0 = *(const float4*)(BASE + offB[0]); C1 = *(const float4*)(BASE + offB[1]); \
    C2 = *(const float4*)(BASE + offB[2]); C3 = *(const float4*)(BASE + offB[3]); \
    BASE += 16384; \
    const f32x2 z2 = {0.f, 0.f}; \
    const f32x2 xF = c0l0 ? St : z2; \
    const f32x2 xS = cTl63 ? Fo : z2; \
    FF[pF]  = l0  ? xF : fi; \
    SS[PHI] = l63 ? xS : sd; \
    FF[pT]  = c0l0 ? So : FF[pT]; \
  }

  if constexpr (LC == 254) {
    // ---------- phase A: T = 0..123, window [kb2, kb2+255], 4 pairs/lane ----------
    const int kb2 = min(max((kmin - 124) & ~1, 0), 768);
    const bool a0l0  = (kb2 == 0)   && l0;
    const bool aTl63 = (kb2 == 768) && l63;

#pragma unroll
    for (int e = 0; e < 4; ++e) {
      const int k = kb2 + 4 * lane + e, m = 2047 - k;
      FF[e] = (f32x2){(k == pA) ? 1.f : 0.f, (k == pB) ? 1.f : 0.f};
      SS[e] = (f32x2){(m == pA) ? 1.f : 0.f, (m == pB) ? 1.f : 0.f};
    }

    // step-invariant per-lane offsets; scalar bases bumped on SALU
    const int ub = (kb2 >> 1) + 2 * lane;
    const unsigned offA0 = (unsigned)((ub & 3) * 2048 + (ub >> 2) * 16);
    const unsigned offA1 = (unsigned)((((ub + 1) & 3)) * 2048 + (((ub + 1)) >> 2) * 16);
    const char* abE = csb + (size_t)t0 * 8192;
    const char* abO = abE + 8192;
    float4 A0E = *(const float4*)(abE + offA0), A1E = *(const float4*)(abE + offA1);
    float4 A0O = *(const float4*)(abO + offA0), A1O = *(const float4*)(abO + offA1);
    abE += 16384; abO += 16384;

#define ROTE4(E, CPp) { \
    const int rF = ((E) - PHI) & 3, rS = ((E) + PHI) & 3; \
    const f32x2 cp_ = (CPp); \
    const f32x2 t_ = pk_smul(cp_, SS[rS]); \
    const f32x2 u_ = pk_smul(cp_, FF[rF]); \
    FF[rF] = pk_cfma(cp_, FF[rF], t_); \
    SS[rS] = pk_cfma_neg(cp_, SS[rS], u_); }

#define ASTEP(PHI_, C0, C1, BASE) { \
    const int PHI = (PHI_); \
    const int pF = (3 - PHI) & 3, pT = (4 - PHI) & 3; \
    ROTE4(0, CP(C0, 0)) ROTE4(1, CP(C0, 1)) \
    ROTE4(2, CP(C1, 0)) ROTE4(3, CP(C1, 1)) \
    const f32x2 Fo = FF[pF], So = SS[PHI], St = FF[pT]; \
    f32x2 fi, sd; \
    fi.x = dppf<DPP_UP>(Fo.x); fi.y = dppf<DPP_UP>(Fo.y); \
    sd.x = dppf<DPP_DN>(So.x); sd.y = dppf<DPP_DN>(So.y); \
    C0 = *(const float4*)(BASE + offA0); C1 = *(const float4*)(BASE + offA1); \
    BASE += 16384; \
    const f32x2 z2 = {0.f, 0.f}; \
    const f32x2 xF = a0l0 ? St : z2; \
    const f32x2 xS = aTl63 ? Fo : z2; \
    FF[pF]  = l0  ? xF : fi; \
    SS[PHI] = l63 ? xS : sd; \
    FF[pT]  = a0l0 ? So : FF[pT]; \
  }

#pragma unroll 1
    for (int it = 0; it < 31; ++it) {
      ASTEP(0, A0E, A1E, abE)
      ASTEP(1, A0O, A1O, abO)
      ASTEP(2, A0E, A1E, abE)
      ASTEP(3, A0O, A1O, abO)
    }

    // ---------- transition at T = 124 (r16-verified) ----------
    {
      const int dlt = kb2 - kb;               // even, >= 0
      const int base_d = 8 * lane - dlt;
      f32x2 nF[8], nS[8];

#define TGETF(E, SR) { \
      const int d_ = base_d + (E); \
      const int sl_ = (d_ >> 2) & 63; \
      f32x2 fv_; \
      fv_.x = __shfl(FF[SR].x, sl_); \
      fv_.y = __shfl(FF[SR].y, sl_); \
      nF[E] = ((unsigned)d_ < 256u) ? fv_ : (f32x2){0.f, 0.f}; }
#define TGETS(E, SR) { \
      const int d_ = base_d + (E); \
      const int sl_ = (d_ >> 2) & 63; \
      f32x2 sv_; \
      sv_.x = __shfl(SS[SR].x, sl_); \
      sv_.y = __shfl(SS[SR].y, sl_); \
      nS[E] = ((unsigned)d_ < 256u) ? sv_ : (f32x2){0.f, 0.f}; }

      if ((dlt & 3) == 0) {
        TGETF(0,0) TGETF(1,1) TGETF(2,2) TGETF(3,3)
        TGETF(4,0) TGETF(5,1) TGETF(6,2) TGETF(7,3)
      } else {
        TGETF(0,2) TGETF(1,3) TGETF(2,0) TGETF(3,1)
        TGETF(4,2) TGETF(5,3) TGETF(6,0) TGETF(7,1)
      }
      FF[4] = nF[0]; FF[5] = nF[1]; FF[6] = nF[2]; FF[7] = nF[3];
      FF[0] = nF[4]; FF[1] = nF[5]; FF[2] = nF[6]; FF[3] = nF[7];
      if ((dlt & 3) == 0) {
        TGETS(0,0) TGETS(1,1) TGETS(2,2) TGETS(3,3)
        TGETS(4,0) TGETS(5,1) TGETS(6,2) TGETS(7,3)
      } else {
        TGETS(0,2) TGETS(1,3) TGETS(2,0) TGETS(3,1)
        TGETS(4,2) TGETS(5,3) TGETS(6,0) TGETS(7,1)
      }
      SS[4] = nS[0]; SS[5] = nS[1]; SS[6] = nS[2]; SS[7] = nS[3];
      SS[0] = nS[4]; SS[1] = nS[5]; SS[2] = nS[6]; SS[3] = nS[7];
    }

    // ---------- phase B: T = 124..253 ----------
    const int kb8 = kb >> 3, mm = (kb >> 1) & 3;
    unsigned offB[4];
#pragma unroll
    for (int ep = 0; ep < 4; ++ep) {
      const int u = mm + ep;
      offB[ep] = (unsigned)((u & 3) * 2048 + (kb8 + (u >> 2)) * 16 + 16 * lane);
    }
    const char* bbE = csb + (size_t)t0 * 8192 + (size_t)124 * 8192;
    const char* bbO = bbE + 8192;
    float4 cE0 = *(const float4*)(bbE + offB[0]), cE1 = *(const float4*)(bbE + offB[1]);
    float4 cE2 = *(const float4*)(bbE + offB[2]), cE3 = *(const float4*)(bbE + offB[3]);
    float4 cO0 = *(const float4*)(bbO + offB[0]), cO1 = *(const float4*)(bbO + offB[1]);
    float4 cO2 = *(const float4*)(bbO + offB[2]), cO3 = *(const float4*)(bbO + offB[3]);
    bbE += 16384; bbO += 16384;

    LSTEP(4, cE0, cE1, cE2, cE3, bbE)
    LSTEP(5, cO0, cO1, cO2, cO3, bbO)
    LSTEP(6, cE0, cE1, cE2, cE3, bbE)
    LSTEP(7, cO0, cO1, cO2, cO3, bbO)
#pragma unroll 1
    for (int it = 0; it < 15; ++it) {
      LSTEP(0, cE0, cE1, cE2, cE3, bbE)
      LSTEP(1, cO0, cO1, cO2, cO3, bbO)
      LSTEP(2, cE0, cE1, cE2, cE3, bbE)
      LSTEP(3, cO0, cO1, cO2, cO3, bbO)
      LSTEP(4, cE0, cE1, cE2, cE3, bbE)
      LSTEP(5, cO0, cO1, cO2, cO3, bbO)
      LSTEP(6, cE0, cE1, cE2, cE3, bbE)
      LSTEP(7, cO0, cO1, cO2, cO3, bbO)
    }
    LSTEP(0, cE0, cE1, cE2, cE3, bbE)
    LSTEP(1, cO0, cO1, cO2, cO3, bbO)
    LSTEP(2, cE0, cE1, cE2, cE3, bbE)
    LSTEP(3, cO0, cO1, cO2, cO3, bbO)
    LSTEP(4, cE0, cE1, cE2, cE3, bbE)
    LSTEP(5, cO0, cO1, cO2, cO3, bbO)
  } else {
    // ---------- plain path (LC = 15) ----------
#pragma unroll
    for (int e = 0; e < 8; ++e) {
      const int k = kb + 8 * lane + e, m = 2047 - k;
      FF[e] = (f32x2){(k == pA) ? 1.f : 0.f, (k == pB) ? 1.f : 0.f};
      SS[e] = (f32x2){(m == pA) ? 1.f : 0.f, (m == pB) ? 1.f : 0.f};
    }
    const int kb8 = kb >> 3, mm = (kb >> 1) & 3;
    unsigned offB[4];
#pragma unroll
    for (int ep = 0; ep < 4; ++ep) {
      const int u = mm + ep;
      offB[ep] = (unsigned)((u & 3) * 2048 + (kb8 + (u >> 2)) * 16 + 16 * lane);
    }
    const char* bbE = csb + (size_t)t0 * 8192;
    const char* bbO = bbE + 8192;
    float4 cE0 = *(const float4*)(bbE + offB[0]), cE1 = *(const float4*)(bbE + offB[1]);
    float4 cE2 = *(const float4*)(bbE + offB[2]), cE3 = *(const float4*)(bbE + offB[3]);
    float4 cO0 = *(const float4*)(bbO + offB[0]), cO1 = *(const float4*)(bbO + offB[1]);
    float4 cO2 = *(const float4*)(bbO + offB[2]), cO3 = *(const float4*)(bbO + offB[3]);
    bbE += 16384; bbO += 16384;

    constexpr int ITERS = LC / 8;
    constexpr int TAIL  = LC & 7;
#pragma unroll 1
    for (int it = 0; it < ITERS; ++it) {
      LSTEP(0, cE0, cE1, cE2, cE3, bbE)
      LSTEP(1, cO0, cO1, cO2, cO3, bbO)
      LSTEP(2, cE0, cE1, cE2, cE3, bbE)
      LSTEP(3, cO0, cO1, cO2, cO3, bbO)
      LSTEP(4, cE0, cE1, cE2, cE3, bbE)
      LSTEP(5, cO0, cO1, cO2, cO3, bbO)
      LSTEP(6, cE0, cE1, cE2, cE3, bbE)
      LSTEP(7, cO0, cO1, cO2, cO3, bbO)
    }
    if constexpr (TAIL >= 1) LSTEP(0, cE0, cE1, cE2, cE3, bbE)
    if constexpr (TAIL >= 2) LSTEP(1, cO0, cO1, cO2, cO3, bbO)
    if constexpr (TAIL >= 3) LSTEP(2, cE0, cE1, cE2, cE3, bbE)
    if constexpr (TAIL >= 4) LSTEP(3, cO0, cO1, cO2, cO3, bbO)
    if constexpr (TAIL >= 5) LSTEP(4, cE0, cE1, cE2, cE3, bbE)
    if constexpr (TAIL >= 6) LSTEP(5, cO0, cO1, cO2, cO3, bbO)
    if constexpr (TAIL >= 7) LSTEP(6, cE0, cE1, cE2, cE3, bbE)
  }

  // readout at T=LC: F elem e in FF[(e-LC)&7]; S elem e in SS[(e+LC)&7].
  constexpr int RPH = LC & 7;
  const int tend = t0 + LC;
  const int rA = (pA == 0) ? 0 : ((pA - 1 - t0 + 4094) % 2047) + 1;
  const int rB = ((pB - 1 - t0 + 4094) % 2047) + 1;
#pragma unroll
  for (int e = 0; e < 8; ++e) {
    const int k = kb + 8 * lane + e;
    const int lF = (k == 0) ? 0 : ((k - 1 - tend + 4094) % 2047) + 1;
    const int lS = ((2046 - k - tend + 4094) % 2047) + 1;
    const f32x2 fv = FF[(e - RPH) & 7];
    const f32x2 sv = SS[(e + RPH) & 7];
    if (rm) {
      out[(size_t)rA * NN + lF] = f2bf(fv.x);
      out[(size_t)rB * NN + lF] = f2bf(fv.y);
      out[(size_t)rA * NN + lS] = f2bf(sv.x);
      out[(size_t)rB * NN + lS] = f2bf(sv.y);
    } else {
      out[(size_t)lF * NN + rA] = f2bf(fv.x);
      out[(size_t)lF * NN + rB] = f2bf(fv.y);
      out[(size_t)lS * NN + rA] = f2bf(sv.x);
      out[(size_t)lS * NN + rB] = f2bf(sv.y);
    }
  }
}

// κ-range of a cyclic position arc [a, a+len-1] in [1..2047], κ(p)=min(p,2047-p)
__device__ __forceinline__ void arc_kr(int a, int len, int& lo, int& hi) {
  int last = a + len - 1; if (last > 2047) last -= 2047;
  const int k1 = min(a, 2047 - a), k2 = min(last, 2047 - last);
  lo = min(k1, k2); hi = max(k1, k2);
  int d;
  d = 1023 - a; if (d < 0) d += 2047; if (d < len) hi = 1023;
  d = 1024 - a; if (d < 0) d += 2047; if (d < len) hi = 1023;
  d = 2047 - a; if (d < 0) d += 2047; if (d < len) lo = 0;
  d = 1    - a; if (d < 0) d += 2047; if (d < len) lo = min(lo, 1);
}

#define BK  32
#define CBM 128
#define CBN 64

// ---- comp: C = A * Bt^T (2048^3), bf16 out, K-tiles band-skipped by cone test.
// This round: BN 128->64 => grid (16,32) = 512 blocks = 2 blocks/CU.
__global__ __launch_bounds__(256) void comp_kernel(
    const unsigned short* __restrict__ A, const unsigned short* __restrict__ B,
    unsigned short* __restrict__ C, int ta, int tb) {
  __shared__ unsigned short As[CBM * BK];   // 8 KB
  __shared__ unsigned short Bs[CBN * BK];   // 4 KB
  const int tid  = threadIdx.x;
  const int lane = tid & 63;
  const int wave = tid >> 6;
  const int bm = blockIdx.x, bn = blockIdx.y;
  const int wm = wave & 1, wn = wave >> 1;

  const int n0 = bn * CBN;
  int qlo, qhi;
  {
    const int nfirst = (n0 == 0) ? 1 : n0;
    const int a = ((nfirst - 1 + tb) % 2047) + 1;
    const int len = (n0 == 0) ? (CBN - 1) : CBN;
    arc_kr(a, len, qlo, qhi);
    if (n0 == 0) qlo = 0;
  }
  const int L = tb - ta;
  const int KAc = max(qlo - L - PADK, 0);
  const int KBc = min(qhi + L + PADK, 1023);

  const int srow = wave * 16 + (lane >> 2);
  const int scol = (lane & 3) * 8;
  const unsigned short* Ag = A + (size_t)(bm * CBM + srow) * NN + scol;
  const unsigned short* Bg = B + (size_t)(bn * CBN + srow) * NN + scol;

  const int fm = lane & 15;
  const int kbr = lane >> 4;

  f32x4 acc[4][2];
#pragma unroll
  for (int a_ = 0; a_ < 4; ++a_)
#pragma unroll
    for (int b_ = 0; b_ < 2; ++b_) acc[a_][b_] = (f32x4){0.f, 0.f, 0.f, 0.f};

  for (int kt = 0; kt < NN / BK; ++kt) {
    const int k0 = kt * BK;
    {
      const int kfirst = (k0 == 0) ? 1 : k0;
      const int a2 = ((kfirst - 1 + ta) % 2047) + 1;
      const int len2 = (k0 == 0) ? (BK - 1) : BK;
      int tlo, thi; arc_kr(a2, len2, tlo, thi);
      if (k0 == 0) tlo = 0;
      if (thi < KAc || tlo > KBc) continue;
    }
#pragma unroll
    for (int it = 0; it < 2; ++it)
      gload_lds16(Ag + (size_t)(it * 64) * NN + k0, &As[wave * 512 + it * 2048]);
    gload_lds16(Bg + k0, &Bs[wave * 512]);
    __syncthreads();

    bf16x8 af[4], bfr[2];
#pragma unroll
    for (int a_ = 0; a_ < 4; ++a_)
      af[a_] = *(const bf16x8*)&As[(wm * 64 + a_ * 16 + fm) * BK + kbr * 8];
#pragma unroll
    for (int b_ = 0; b_ < 2; ++b_)
      bfr[b_] = *(const bf16x8*)&Bs[(wn * 32 + b_ * 16 + fm) * BK + kbr * 8];
#pragma unroll
    for (int a_ = 0; a_ < 4; ++a_)
#pragma unroll
      for (int b_ = 0; b_ < 2; ++b_)
        acc[a_][b_] = __builtin_amdgcn_mfma_f32_16x16x32_bf16(af[a_], bfr[b_], acc[a_][b_], 0, 0, 0);
    __syncthreads();
  }

  const int row_in = (lane >> 4) * 4;
#pragma unroll
  for (int a_ = 0; a_ < 4; ++a_) {
#pragma unroll
    for (int b_ = 0; b_ < 2; ++b_) {
      const int gn = bn * CBN + wn * 32 + b_ * 16 + fm;
#pragma unroll
      for (int vv = 0; vv < 4; ++vv) {
        const int gm = bm * CBM + wm * 64 + a_ * 16 + row_in + vv;
        C[(size_t)gm * NN + gn] = f2bf(acc[a_][b_][vv]);
      }
    }
  }
}

#define BM 128
#define BN 128

// ---- final: out = x_bf16 * U^T + bias (fp32 out). Verified rounds 1-16.
__global__ __launch_bounds__(256) void gemm_kernel(
    const unsigned short* __restrict__ A, const unsigned short* __restrict__ B,
    const float* __restrict__ bias, float* __restrict__ C) {
  __shared__ unsigned short As[BM * BK];
  __shared__ unsigned short Bs[BN * BK];
  const int tid  = threadIdx.x;
  const int lane = tid & 63;
  const int wave = tid >> 6;
  const int bm = blockIdx.x, bn = blockIdx.y;
  const int wm = wave & 1, wn = wave >> 1;

  const int srow = wave * 16 + (lane >> 2);
  const int scol = (lane & 3) * 8;
  const unsigned short* Ag = A + (size_t)(bm * BM + srow) * NN + scol;
  const unsigned short* Bg = B + (size_t)(bn * BN + srow) * NN + scol;

  const int fm = lane & 15;
  const int kbr = lane >> 4;

  f32x4 acc[4][4];
#pragma unroll
  for (int a_ = 0; a_ < 4; ++a_)
#pragma unroll
    for (int b_ = 0; b_ < 4; ++b_) acc[a_][b_] = (f32x4){0.f, 0.f, 0.f, 0.f};

  for (int kt = 0; kt < NN / BK; ++kt) {
    const int k0 = kt * BK;
#pragma unroll
    for (int it = 0; it < 2; ++it) {
      gload_lds16(Ag + (size_t)(it * 64) * NN + k0, &As[wave * 512 + it * 2048]);
      gload_lds16(Bg + (size_t)(it * 64) * NN + k0, &Bs[wave * 512 + it * 2048]);
    }
    __syncthreads();

    bf16x8 af[4], bfr[4];
#pragma unroll
    for (int a_ = 0; a_ < 4; ++a_)
      af[a_] = *(const bf16x8*)&As[(wm * 64 + a_ * 16 + fm) * BK + kbr * 8];
#pragma unroll
    for (int b_ = 0; b_ < 4; ++b_)
      bfr[b_] = *(const bf16x8*)&Bs[(wn * 64 + b_ * 16 + fm) * BK + kbr * 8];
#pragma unroll
    for (int a_ = 0; a_ < 4; ++a_)
#pragma unroll
      for (int b_ = 0; b_ < 4; ++b_)
        acc[a_][b_] = __builtin_amdgcn_mfma_f32_16x16x32_bf16(af[a_], bfr[b_], acc[a_][b_], 0, 0, 0);
    __syncthreads();
  }

  const int row_in = (lane >> 4) * 4;
#pragma unroll
  for (int a_ = 0; a_ < 4; ++a_) {
#pragma unroll
    for (int b_ = 0; b_ < 4; ++b_) {
      const int gn = bn * BN + wn * 64 + b_ * 16 + fm;
      const float bv = bias[gn];
#pragma unroll
      for (int vv = 0; vv < 4; ++vv) {
        const int gm = bm * BM + wm * 64 + a_ * 16 + row_in + vv;
        C[(size_t)gm * NN + gn] = acc[a_][b_][vv] + bv;
      }
    }
  }
}

extern "C" void kernel_launch(void* const* d_in, const int* in_sizes, int n_in,
                              void* d_out, int out_size, void* d_ws, size_t ws_size,
                              hipStream_t stream) {
  const float* x      = (const float*)d_in[0];
  const float* angles = (const float*)d_in[1];
  const float* bias   = (const float*)d_in[2];
  float* out = (float*)d_out;

  char* ws = (char*)d_ws;
  unsigned short* P0  = (unsigned short*)(ws + 0);         //  8,388,608
  unsigned short* P1  = (unsigned short*)(ws + 8388608);   //  8,388,608
  char*           cs  = ws + 16777216;                     // 16,809,984 (2052 slices)
  unsigned short* B7  = (unsigned short*)(ws + 33587200);  //  8,388,608
  unsigned short* B8  = (unsigned short*)(ws + 41975808);  //  8,388,608 -> end 50,364,416
  unsigned short* xb  = (unsigned short*)(ws + 16777216);  // overlay (after comps)

  // B1..B6 live in d_out (final gemm overwrites all of d_out at the end)
  char* ob = (char*)d_out;
  unsigned short* B1 = (unsigned short*)(ob + 0);
  unsigned short* B2 = (unsigned short*)(ob + 8388608);
  unsigned short* B3 = (unsigned short*)(ob + 16777216);
  unsigned short* B4 = (unsigned short*)(ob + 25165824);
  unsigned short* B5 = (unsigned short*)(ob + 33554432);
  unsigned short* B6 = (unsigned short*)(ob + 41943040);   // end 50,331,648

  prep_kernel<<<dim3(8188), dim3(256), 0, stream>>>(angles, (float2*)cs);
  zero_kernel<<<dim3(2048), dim3(256), 0, stream>>>((uint4*)ob, 50331648 / 16);
  zero_kernel<<<dim3(1024), dim3(256), 0, stream>>>((uint4*)P0, 8388608 / 16);
  zero_kernel<<<dim3(1024), dim3(256), 0, stream>>>((uint4*)(ws + 33587200), 16777216 / 16);

  // single merged leaf dispatch, XCD-aligned: chunk = bid & 7 (one chunk per XCD)
  LeafOuts lo_main;
  lo_main.p[0] = P0; lo_main.p[1] = B1; lo_main.p[2] = B2; lo_main.p[3] = B3;
  lo_main.p[4] = B4; lo_main.p[5] = B5; lo_main.p[6] = B6; lo_main.p[7] = B7;
  leaf_kernel<254><<<dim3(2048), dim3(256), 0, stream>>>(cs, lo_main, 0, 1, 7, 3);
  // chunk 8 (15 steps)
  LeafOuts lo_tail;
  for (int i = 0; i < 8; ++i) lo_tail.p[i] = B8;
  leaf_kernel<15><<<dim3(256), dim3(256), 0, stream>>>(cs, lo_tail, 8, 0, 0, 0);

  // composition chain: P = B0 * B1 * ... * B8  (comp grid now 16x32, 2 blocks/CU)
  comp_kernel<<<dim3(16, 32), dim3(256), 0, stream>>>(P0, B1, P1,  254,  508);
  comp_kernel<<<dim3(16, 32), dim3(256), 0, stream>>>(P1, B2, P0,  508,  762);
  comp_kernel<<<dim3(16, 32), dim3(256), 0, stream>>>(P0, B3, P1,  762, 1016);
  comp_kernel<<<dim3(16, 32), dim3(256), 0, stream>>>(P1, B4, P0, 1016, 1270);
  comp_kernel<<<dim3(16, 32), dim3(256), 0, stream>>>(P0, B5, P1, 1270, 1524);
  comp_kernel<<<dim3(16, 32), dim3(256), 0, stream>>>(P1, B6, P0, 1524, 1778);
  comp_kernel<<<dim3(16, 32), dim3(256), 0, stream>>>(P0, B7, P1, 1778, 2032);
  comp_kernel<<<dim3(16, 32), dim3(256), 0, stream>>>(P1, B8, P0, 2032, 2047);

  // x -> bf16 into overlay (cs/B7/B8 dead now), then final GEMM overwrites d_out
  cvt_kernel<<<dim3(16384), dim3(256), 0, stream>>>((const float4*)x, (ushort4*)xb,
                                                    MROWS * NN / 4);
  gemm_kernel<<<dim3(MROWS / BM, NN / BN), dim3(256), 0, stream>>>(xb, P0, bias, out);
}